// Round 7
// baseline (696.467 us; speedup 1.0000x reference)
//
#include <hip/hip_runtime.h>
#include <hip/hip_bf16.h>
#include <hip/hip_cooperative_groups.h>
#include <math.h>

namespace cg = cooperative_groups;

#define D_MODEL   256
#define D_STATE   64
#define D_CONV    4
#define D_INNER   512
#define HEADDIM   64
#define NHEADS    8
#define CONV_DIM  640     // D_INNER + 2*D_STATE
#define D_IN_PROJ 1160    // 2*D_INNER + 2*D_STATE + NHEADS
#define ZXP       1280    // padded in_proj N (10 x 128 tiles)
#define SEQLEN    1024
#define BATCH     8
#define NROWS     8192    // BATCH * SEQLEN
#define EPS       1e-5f
#define CHUNK     64
#define NCHUNK    (SEQLEN / CHUNK)   // 16

typedef __attribute__((ext_vector_type(8))) short bf16x8;
typedef __attribute__((ext_vector_type(4))) short s16x4;
typedef __attribute__((ext_vector_type(8))) unsigned short u16x8;
typedef __attribute__((ext_vector_type(4))) unsigned short u16x4;
typedef __attribute__((ext_vector_type(4))) float f32x4;
typedef unsigned int u32;
typedef unsigned short u16;

__device__ __forceinline__ void cp16(const short* g, short* l) {
    __builtin_amdgcn_global_load_lds((const __attribute__((address_space(1))) u32*)g,
                                     (__attribute__((address_space(3))) u32*)l, 16, 0, 0);
}
__device__ __forceinline__ u16 bfc(float f) {
    union { __hip_bfloat16 h; u16 u; } cv;
    cv.h = __float2bfloat16(f);
    return cv.u;
}
__device__ __forceinline__ float bf2f(u16 u) {
    union { u32 v; float f; } cv;
    cv.v = ((u32)u) << 16;
    return cv.f;
}
__device__ __forceinline__ float silu_f(float a) {
    return a * __builtin_amdgcn_rcpf(1.f + __expf(-a));
}

// 64-col bf16 LDS tile, XOR-octet swizzle
__device__ __forceinline__ int swz(int row, int col) {
    return row * 64 + (((col & 56) ^ ((row & 7) << 3)) | (col & 7));
}
__device__ __forceinline__ bf16x8 ldfrag(const short* base, int row, int oct) {
    return *(const bf16x8*)&base[row * 64 + ((oct * 8) ^ ((row & 7) * 8))];
}
__device__ __forceinline__ void wr2u(short* base, int row, int col2, u16 a, u16 b) {
    int idx = row * 64 + (((col2 & 56) ^ ((row & 7) << 3)) | (col2 & 6));
    *(u32*)&base[idx] = (u32)a | ((u32)b << 16);
}

#define NX_C  (NROWS * D_MODEL)
#define NWI_C (2 * ZXP * D_MODEL)
#define NWO_C (2 * D_MODEL * D_INNER)
#define TOT_C (NX_C + NWI_C + NWO_C)

// ---------------------------------------------------------------------------
// Cooperative mega-kernel: cast, then 2 x {in_proj GEMM, conv B/C, SSD intra,
// state scan, finish+out_proj}, grid.sync() between phases. 256 blocks x 512.
// LDS union: max phase = intra (2 halves x 34816 B) = 69632 B.
// ---------------------------------------------------------------------------
__global__ __launch_bounds__(512) void mamba_mega(
    const float* __restrict__ x, const float* __restrict__ in_proj_w,
    const float* __restrict__ conv_w, const float* __restrict__ conv_b,
    const float* __restrict__ dt_bias, const float* __restrict__ A_log,
    const float* __restrict__ Dp, const float* __restrict__ norm_w,
    const float* __restrict__ out_proj_w, float* __restrict__ out,
    u16* __restrict__ buf_zx, u16* __restrict__ buf_bb, u16* __restrict__ buf_cb,
    u16* __restrict__ buf_ys, u16* __restrict__ buf_S, u16* __restrict__ buf_hb,
    u16* __restrict__ buf_wi, u16* __restrict__ buf_wo,
    float* __restrict__ buf_dt, float* __restrict__ buf_a)
{
    cg::grid_group grid = cg::this_grid();
    __shared__ __align__(16) short smem[34816];   // 69632 B

    const int tid  = threadIdx.x;
    const int bid  = blockIdx.x;
    const int half = tid >> 8;          // 0/1: 256-thread half-block unit
    const int ltid = tid & 255;
    const int U    = (bid << 1) | half; // unit id 0..511

    // ===== phase: cast (x -> hb bf16, in_proj_w -> wi padded, out_proj_w -> wo)
    for (int idx0 = bid * 512 + tid; idx0 < TOT_C; idx0 += 256 * 512) {
        int idx = idx0;
        if (idx < NX_C) { buf_hb[idx] = bfc(x[idx]); continue; }
        idx -= NX_C;
        if (idx < NWI_C) {
            int k  = idx & 255;
            int rb = idx >> 8;
            int r  = rb % ZXP;
            int blk = rb / ZXP;
            float v = (r < D_IN_PROJ)
                ? in_proj_w[(size_t)blk * D_IN_PROJ * D_MODEL + (size_t)r * D_MODEL + k] : 0.f;
            buf_wi[idx] = bfc(v);
            continue;
        }
        idx -= NWI_C;
        buf_wo[idx] = bfc(out_proj_w[idx]);
    }
    grid.sync();

    for (int it = 0; it < 2; it++) {
        const u16*  wi_i  = buf_wi + (size_t)it * ZXP * D_MODEL;
        const u16*  wo_i  = buf_wo + (size_t)it * D_MODEL * D_INNER;
        const float* cw_i = conv_w + (size_t)it * CONV_DIM * D_CONV;
        const float* cb_i = conv_b + it * CONV_DIM;
        const float* dtb_i = dt_bias + it * NHEADS;
        const float* Al_i  = A_log + it * NHEADS;
        const float* Dp_i  = Dp + it * NHEADS;
        const float* nw_i  = norm_w + it * D_INNER;

        // ===== phase: in_proj GEMM  zx[8192x1280] = hb[8192x256] @ wi^T =====
        // 640 tiles over 512 units; units<128 (blocks<64) do 2, rest do 1.
        // Both halves of a block do the same count -> uniform __syncthreads.
        {
            short* As = smem + half * 16384;
            short* Ws = As + 8192;
            const short* Abase = (const short*)buf_hb;
            const short* Wbase = (const short*)wi_i;
            const int wave = ltid >> 6, lane = ltid & 63;
            const int wm = (wave & 1) * 64;
            const int wn = (wave >> 1) * 64;
            const int lm = lane & 15, lq = lane >> 4;
            const int sr = ltid >> 2, sk = (ltid & 3) * 8;
            const int ntile = (bid < 64) ? 2 : 1;
            for (int t = 0; t < ntile; t++) {
                const int tile = (bid < 64) ? (2 * U + t) : (128 + U);
                const int n0 = (tile % 10) * 128;
                const int m0 = (tile / 10) * 128;
                const short* ga = Abase + (size_t)(m0 + sr) * D_MODEL + sk;
                const short* gw = Wbase + (size_t)(n0 + sr) * D_MODEL + sk;
                short* la = &As[ltid * 8];
                short* lw = &Ws[ltid * 8];
                f32x4 acc[4][4] = {};
                for (int k0 = 0; k0 < D_MODEL; k0 += 32) {
                    cp16(ga,                       la);
                    cp16(ga + (size_t)64 * D_MODEL, la + 64 * 32);
                    cp16(gw,                       lw);
                    cp16(gw + (size_t)64 * D_MODEL, lw + 64 * 32);
                    ga += 32; gw += 32;
                    __syncthreads();
                    bf16x8 af[4], bfr[4];
                    #pragma unroll
                    for (int i = 0; i < 4; i++) {
                        af[i]  = *(const bf16x8*)&As[(wm + i * 16 + lm) * 32 + lq * 8];
                        bfr[i] = *(const bf16x8*)&Ws[(wn + i * 16 + lm) * 32 + lq * 8];
                    }
                    #pragma unroll
                    for (int i = 0; i < 4; i++)
                        #pragma unroll
                        for (int j = 0; j < 4; j++)
                            acc[i][j] = __builtin_amdgcn_mfma_f32_16x16x32_bf16(af[i], bfr[j], acc[i][j], 0, 0, 0);
                    __syncthreads();
                }
                #pragma unroll
                for (int i = 0; i < 4; i++)
                    #pragma unroll
                    for (int r = 0; r < 4; r++) {
                        int m = m0 + wm + i * 16 + lq * 4 + r;
                        #pragma unroll
                        for (int j = 0; j < 4; j++) {
                            int n = n0 + wn + j * 16 + lm;
                            float v = acc[i][j][r];
                            buf_zx[(size_t)m * ZXP + n] = bfc(v);
                            if (n >= D_IN_PROJ - NHEADS && n < D_IN_PROJ)
                                buf_dt[(size_t)m * NHEADS + (n - (D_IN_PROJ - NHEADS))] = v;
                        }
                    }
            }
        }
        grid.sync();

        // ===== phase: conv B/C (slim, channels [512,640) of xBC) =====
        if (U < 256) {
            int idx = U * 256 + ltid;                 // 0..65535
            int cc  = 512 + (idx & 31) * 4;
            int r4  = (idx >> 5) * 4;
            int l4  = r4 & (SEQLEN - 1);
            float wt[4][4];
            #pragma unroll
            for (int k = 0; k < 4; k++)
                *(float4*)&wt[k][0] = *(const float4*)&cw_i[(cc + k) * 4];
            float4 cbv = *(const float4*)&cb_i[cc];
            float cbk[4] = {cbv.x, cbv.y, cbv.z, cbv.w};
            const u16* base = buf_zx + (size_t)r4 * ZXP + D_INNER + cc;
            u16x4 hrow[7];
            #pragma unroll
            for (int k = 0; k < 3; k++) {
                if (l4 != 0) hrow[k] = *(const u16x4*)&base[(k - 3) * ZXP];
                else { hrow[k][0] = 0; hrow[k][1] = 0; hrow[k][2] = 0; hrow[k][3] = 0; }
            }
            #pragma unroll
            for (int k = 3; k < 7; k++)
                hrow[k] = *(const u16x4*)&base[(k - 3) * ZXP];
            const bool isB = (cc < 512 + D_STATE);
            u16* dst = isB ? (buf_bb + (size_t)r4 * 64 + (cc - 512))
                           : (buf_cb + (size_t)r4 * 64 + (cc - 576));
            #pragma unroll
            for (int rr = 0; rr < 4; rr++) {
                u16x4 o;
                #pragma unroll
                for (int k = 0; k < 4; k++) {
                    float acc = cbk[k];
                    #pragma unroll
                    for (int tap = 0; tap < 4; tap++)
                        acc = fmaf(bf2f(hrow[rr + tap][k]), wt[k][tap], acc);
                    o[k] = bfc(silu_f(acc));
                }
                *(u16x4*)&dst[(size_t)rr * 64] = o;
            }
        }
        grid.sync();

        // ===== phase: SSD intra (1024 tiles, 2 per 256-thread half) =====
        {
            short* Xt  = smem + half * 17408;
            short* Bn  = Xt + 4096;
            short* Cn  = Bn + 4096;
            short* BTw = Cn + 4096;
            float* fb  = (float*)(BTw + 4096);     // 512 floats
            float* cums  = fb;
            float* dts_s = fb + 64;
            float* ws_s  = fb + 128;
            float4* wls  = (float4*)(fb + 192);    // 64 float4
            float* bls   = fb + 448;               // 64 floats

            for (int t = 0; t < 2; t++) {
                const int tile = U * 2 + t;
                const int h = tile & 7;
                const int c = (tile >> 3) & 15;
                const int b = tile >> 7;
                const int row0 = b * SEQLEN + c * CHUNK;

                if (ltid < 64) {
                    const float A = -__expf(Al_i[h] * 1.44269504089f);
                    float raw = buf_dt[(size_t)(row0 + ltid) * NHEADS + h] + dtb_i[h];
                    float dtv = (raw > 20.f) ? raw : log1pf(__expf(raw));
                    float v = dtv * A;
                    #pragma unroll
                    for (int off = 1; off < 64; off <<= 1) {
                        float o = __shfl_up(v, off, 64);
                        if (ltid >= off) v += o;
                    }
                    float tot = __shfl(v, 63, 64);
                    cums[ltid]  = v;
                    dts_s[ltid] = dtv;
                    ws_s[ltid]  = __expf(tot - v) * dtv;
                    buf_a[(size_t)(b * NHEADS + h) * SEQLEN + c * CHUNK + ltid] = __expf(v);
                } else if (ltid < 128) {
                    int k = ltid - 64;
                    int ch = h * HEADDIM + k;
                    wls[k] = *(const float4*)&cw_i[ch * 4];
                    bls[k] = cb_i[ch];
                }
                __syncthreads();

                {   // stage B/C from compact; fused conv+SiLU for x from zx
                    const int t2 = (ltid >> 3) * 2;
                    const int c8 = (ltid & 7) * 8;
                    const int lb = c * CHUNK + t2;
                    u16x8 bv0 = *(const u16x8*)&buf_bb[(size_t)(row0 + t2) * 64 + c8];
                    u16x8 bv1 = *(const u16x8*)&buf_bb[(size_t)(row0 + t2 + 1) * 64 + c8];
                    u16x8 cv0 = *(const u16x8*)&buf_cb[(size_t)(row0 + t2) * 64 + c8];
                    u16x8 cv1 = *(const u16x8*)&buf_cb[(size_t)(row0 + t2 + 1) * 64 + c8];
                    *(u16x8*)&Bn[swz(t2,     c8)] = bv0;
                    *(u16x8*)&Bn[swz(t2 + 1, c8)] = bv1;
                    *(u16x8*)&Cn[swz(t2,     c8)] = cv0;
                    *(u16x8*)&Cn[swz(t2 + 1, c8)] = cv1;
                    float w0 = ws_s[t2], w1 = ws_s[t2 + 1];

                    const u16* p = buf_zx + (size_t)(row0 + t2) * ZXP + D_INNER + h * HEADDIM + c8;
                    u16x8 zz;
                    #pragma unroll
                    for (int q = 0; q < 8; q++) zz[q] = 0;
                    u16x8 r0 = (lb >= 3) ? *(const u16x8*)(p - 3 * ZXP) : zz;
                    u16x8 r1 = (lb >= 2) ? *(const u16x8*)(p - 2 * ZXP) : zz;
                    u16x8 r2 = (lb >= 1) ? *(const u16x8*)(p - 1 * ZXP) : zz;
                    u16x8 r3 = *(const u16x8*)p;
                    u16x8 r4 = *(const u16x8*)(p + ZXP);
                    #pragma unroll
                    for (int k = 0; k < 8; k++) {
                        float4 w4  = wls[c8 + k];
                        float bias = bls[c8 + k];
                        float a0 = bias, a1 = bias;
                        a0 = fmaf(bf2f(r0[k]), w4.x, a0);
                        a0 = fmaf(bf2f(r1[k]), w4.y, a0);
                        a0 = fmaf(bf2f(r2[k]), w4.z, a0);
                        a0 = fmaf(bf2f(r3[k]), w4.w, a0);
                        a1 = fmaf(bf2f(r1[k]), w4.x, a1);
                        a1 = fmaf(bf2f(r2[k]), w4.y, a1);
                        a1 = fmaf(bf2f(r3[k]), w4.z, a1);
                        a1 = fmaf(bf2f(r4[k]), w4.w, a1);
                        wr2u(Xt,  c8 + k, t2, bfc(silu_f(a0)), bfc(silu_f(a1)));
                        wr2u(BTw, c8 + k, t2, bfc(bf2f(bv0[k]) * w0), bfc(bf2f(bv1[k]) * w1));
                    }
                }
                __syncthreads();

                const int lane = ltid & 63, w = ltid >> 6;
                const int lm = lane & 15, lq = lane >> 4;
                const int tau0 = 16 * w + lq * 4;

                bf16x8 aG0 = ldfrag(Bn, 16 * w + lm, lq);
                bf16x8 aG1 = ldfrag(Bn, 16 * w + lm, 4 + lq);
                f32x4 g[4] = {};
                #pragma unroll
                for (int j = 0; j < 4; j++) {
                    g[j] = __builtin_amdgcn_mfma_f32_16x16x32_bf16(aG0, ldfrag(Cn, 16 * j + lm, lq),     g[j], 0, 0, 0);
                    g[j] = __builtin_amdgcn_mfma_f32_16x16x32_bf16(aG1, ldfrag(Cn, 16 * j + lm, 4 + lq), g[j], 0, 0, 0);
                }
                float ctau[4], dtau[4];
                *(float4*)&ctau[0] = *(const float4*)&cums[tau0];
                *(float4*)&dtau[0] = *(const float4*)&dts_s[tau0];
                s16x4 mp[4];
                #pragma unroll
                for (int j = 0; j < 4; j++) {
                    int tt = 16 * j + lm;
                    float ct = cums[tt];
                    #pragma unroll
                    for (int r = 0; r < 4; r++) {
                        int tau = tau0 + r;
                        float m = (tt >= tau) ? g[j][r] * __expf(ct - ctau[r]) * dtau[r] : 0.f;
                        mp[j][r] = (short)bfc(m);
                    }
                }
                __syncthreads();
                #pragma unroll
                for (int j = 0; j < 4; j++)
                    *(s16x4*)&Cn[swz(16 * j + lm, tau0)] = mp[j];   // MT[t][tau]
                __syncthreads();

                bf16x8 aY0 = ldfrag(Cn,  16 * w + lm, lq);
                bf16x8 aY1 = ldfrag(Cn,  16 * w + lm, 4 + lq);
                bf16x8 aS0 = ldfrag(BTw, 16 * w + lm, lq);
                bf16x8 aS1 = ldfrag(BTw, 16 * w + lm, 4 + lq);
                f32x4 yv[4] = {}, sv[4] = {};
                #pragma unroll
                for (int j = 0; j < 4; j++) {
                    bf16x8 xf0 = ldfrag(Xt, 16 * j + lm, lq);
                    bf16x8 xf1 = ldfrag(Xt, 16 * j + lm, 4 + lq);
                    yv[j] = __builtin_amdgcn_mfma_f32_16x16x32_bf16(aY0, xf0, yv[j], 0, 0, 0);
                    yv[j] = __builtin_amdgcn_mfma_f32_16x16x32_bf16(aY1, xf1, yv[j], 0, 0, 0);
                    sv[j] = __builtin_amdgcn_mfma_f32_16x16x32_bf16(aS0, xf0, sv[j], 0, 0, 0);
                    sv[j] = __builtin_amdgcn_mfma_f32_16x16x32_bf16(aS1, xf1, sv[j], 0, 0, 0);
                }
                const float Dh = Dp_i[h];
                const int mrow = 16 * w + lq * 4;
                #pragma unroll
                for (int j = 0; j < 4; j++)
                    #pragma unroll
                    for (int r = 0; r < 4; r++) {
                        float xv = bf2f((u16)Xt[swz(16 * j + lm, mrow + r)]);
                        buf_ys[(size_t)(row0 + mrow + r) * D_INNER + h * HEADDIM + 16 * j + lm]
                            = bfc(yv[j][r] + Dh * xv);
                    }
                u16* sb = buf_S + (size_t)((b * NCHUNK + c) * NHEADS + h) * 4096;
                #pragma unroll
                for (int j = 0; j < 4; j++)
                    #pragma unroll
                    for (int r = 0; r < 4; r++)
                        sb[(mrow + r) * 64 + 16 * j + lm] = bfc(sv[j][r]);
                __syncthreads();   // LDS reuse safe for next tile
            }
        }
        grid.sync();

        // ===== phase: state prefix scan (256 units) =====
        if (U < 256) {
            const int q  = U & 3;
            const int bh = U >> 2;
            const int b  = bh >> 3, h = bh & 7;
            const int base = q * 1024 + ltid * 4;
            u16x4 v[NCHUNK];
            float atot[NCHUNK];
            #pragma unroll
            for (int c = 0; c < NCHUNK; c++) {
                v[c] = *(const u16x4*)&buf_S[(size_t)((b * NCHUNK + c) * NHEADS + h) * 4096 + base];
                atot[c] = buf_a[(size_t)bh * SEQLEN + c * CHUNK + 63];
            }
            float run[4] = {0.f, 0.f, 0.f, 0.f};
            #pragma unroll
            for (int c = 0; c < NCHUNK; c++) {
                u16x4 pv;
                #pragma unroll
                for (int k = 0; k < 4; k++) pv[k] = bfc(run[k]);
                *(u16x4*)&buf_S[(size_t)((b * NCHUNK + c) * NHEADS + h) * 4096 + base] = pv;
                #pragma unroll
                for (int k = 0; k < 4; k++)
                    run[k] = fmaf(atot[c], run[k], bf2f(v[c][k]));
            }
        }
        grid.sync();

        // ===== phase: finish + out_proj (R4 structure: 256 blocks x 512 thr) =====
        {
            const int half_f = bid & 1;
            const int c      = (bid >> 1) & 15;
            const int b      = bid >> 5;
            const int row0   = b * SEQLEN + c * CHUNK + half_f * 32;

            short* y_lds = smem;                 // 16384 shorts (32 KB)
            short* reg2  = smem + 16384;         // 16384 shorts (32 KB)
            short* Ct    = reg2;
            short* STs   = reg2 + 32 * 64;
            short* Ws    = reg2;
            float* fb2   = (float*)(smem + 32768);
            float* a_s   = fb2;                  // 256
            float* nw_s  = fb2 + 256;            // 512
            float* ps    = fb2 + 768;            // 128
            float* scl   = fb2 + 896;            // 32

            const int lane = tid & 63, w = tid >> 6;
            const int lm = lane & 15, lq = lane >> 4;
            const int rf  = w & 1;
            const int cf4 = w >> 1;

            nw_s[tid] = nw_i[tid];
            if (tid < 256) {
                int t2 = tid >> 3, n8 = (tid & 7) * 8;
                *(u16x8*)&Ct[swz(t2, n8)] = *(const u16x8*)&buf_cb[(size_t)(row0 + t2) * 64 + n8];
                a_s[tid] = buf_a[(size_t)(b * NHEADS + (tid >> 5)) * SEQLEN + c * CHUNK + half_f * 32 + (tid & 31)];
                const u16* sb = buf_S + (size_t)((b * NCHUNK + c) * NHEADS) * 4096;
                int n2 = (tid >> 3) * 2, p8 = (tid & 7) * 8;
                u16x8 s0 = *(const u16x8*)&sb[(size_t)n2 * 64 + p8];
                u16x8 s1 = *(const u16x8*)&sb[(size_t)(n2 + 1) * 64 + p8];
                #pragma unroll
                for (int k = 0; k < 8; k++)
                    wr2u(STs, p8 + k, n2, s0[k], s1[k]);
            }
            __syncthreads();

            bf16x8 aC0 = ldfrag(Ct, 16 * rf + lm, lq);
            bf16x8 aC1 = ldfrag(Ct, 16 * rf + lm, 4 + lq);
            float ssloc[4] = {0.f, 0.f, 0.f, 0.f};

            for (int h = 0; h < 8; h++) {
                const int n = cf4 * 16 + lm;
                f32x4 Uacc = {};
                Uacc = __builtin_amdgcn_mfma_f32_16x16x32_bf16(aC0, ldfrag(STs, n, lq),     Uacc, 0, 0, 0);
                Uacc = __builtin_amdgcn_mfma_f32_16x16x32_bf16(aC1, ldfrag(STs, n, 4 + lq), Uacc, 0, 0, 0);
                __syncthreads();
                if (h < 7 && tid < 256) {
                    const u16* sb = buf_S + (size_t)((b * NCHUNK + c) * NHEADS + h + 1) * 4096;
                    int n2 = (tid >> 3) * 2, p8 = (tid & 7) * 8;
                    u16x8 s0 = *(const u16x8*)&sb[(size_t)n2 * 64 + p8];
                    u16x8 s1 = *(const u16x8*)&sb[(size_t)(n2 + 1) * 64 + p8];
                    #pragma unroll
                    for (int k = 0; k < 8; k++)
                        wr2u(STs, p8 + k, n2, s0[k], s1[k]);
                }
                {
                    const int col = h * 64 + cf4 * 16 + lm;
                    const float nwv = nw_s[col];
                    #pragma unroll
                    for (int r = 0; r < 4; r++) {
                        int row = 16 * rf + lq * 4 + r;
                        size_t grow = (size_t)(row0 + row);
                        float u = Uacc[r] * a_s[h * 32 + row] + bf2f(buf_ys[grow * D_INNER + col]);
                        float zv = bf2f(buf_zx[grow * ZXP + col]);
                        float v = u * silu_f(zv);
                        ssloc[r] = fmaf(v, v, ssloc[r]);
                        y_lds[row * 512 + ((((col >> 3) ^ (row & 7)) << 3) | (col & 7))] = (short)bfc(v * nwv);
                    }
                }
                __syncthreads();
            }

            #pragma unroll
            for (int r = 0; r < 4; r++) {
                float s = ssloc[r];
                s += __shfl_xor(s, 1, 64); s += __shfl_xor(s, 2, 64);
                s += __shfl_xor(s, 4, 64); s += __shfl_xor(s, 8, 64);
                if (lm == 0) ps[cf4 * 32 + 16 * rf + lq * 4 + r] = s;
            }
            __syncthreads();
            if (tid < 32)
                scl[tid] = rsqrtf((ps[tid] + ps[32 + tid] + ps[64 + tid] + ps[96 + tid])
                                  * (1.f / (float)D_INNER) + EPS);
            __syncthreads();

            f32x4 acc[4] = {};
            const int arow = 16 * rf + lm;
            for (int kk = 0; kk < 8; kk++) {
                {
                    int rr = tid >> 3;
                    int oc = tid & 7;
                    #pragma unroll
                    for (int q = 0; q < 4; q++) {
                        int row = rr + q * 64;
                        const u16* src = wo_i + (size_t)row * 512 + kk * 64 + ((oc ^ (row & 7)) * 8);
                        cp16((const short*)src, &Ws[q * 4096 + tid * 8]);
                    }
                }
                __syncthreads();
                bf16x8 aY0 = *(const bf16x8*)&y_lds[arow * 512 + ((kk * 8) | (lq       ^ (arow & 7))) * 8];
                bf16x8 aY1 = *(const bf16x8*)&y_lds[arow * 512 + ((kk * 8) | ((4 + lq) ^ (arow & 7))) * 8];
                #pragma unroll
                for (int j = 0; j < 4; j++) {
                    int n = cf4 * 64 + j * 16 + lm;
                    acc[j] = __builtin_amdgcn_mfma_f32_16x16x32_bf16(aY0, ldfrag(Ws, n, lq),     acc[j], 0, 0, 0);
                    acc[j] = __builtin_amdgcn_mfma_f32_16x16x32_bf16(aY1, ldfrag(Ws, n, 4 + lq), acc[j], 0, 0, 0);
                }
                __syncthreads();
            }
            const int mrow = 16 * rf + lq * 4;
            #pragma unroll
            for (int r = 0; r < 4; r++) {
                float scale = scl[mrow + r];
                size_t m = (size_t)(row0 + mrow + r);
                #pragma unroll
                for (int j = 0; j < 4; j++) {
                    int n = cf4 * 64 + j * 16 + lm;
                    float v = acc[j][r] * scale;
                    if (it == 1) out[m * D_MODEL + n] = v;
                    else         buf_hb[m * D_MODEL + n] = bfc(v);
                }
            }
        }
        grid.sync();
    }
}

// ---------------------------------------------------------------------------
extern "C" void kernel_launch(void* const* d_in, const int* in_sizes, int n_in,
                              void* d_out, int out_size, void* d_ws, size_t ws_size,
                              hipStream_t stream) {
    const float* x          = (const float*)d_in[0];
    const float* in_proj_w  = (const float*)d_in[1];
    const float* conv_w     = (const float*)d_in[2];
    const float* conv_b     = (const float*)d_in[3];
    const float* dt_bias    = (const float*)d_in[4];
    const float* A_log      = (const float*)d_in[5];
    const float* Dp         = (const float*)d_in[6];
    const float* norm_w     = (const float*)d_in[7];
    const float* out_proj_w = (const float*)d_in[8];
    float* out = (float*)d_out;

    u16*   buf_zx = (u16*)d_ws;                                      // 8192 x 1280 bf16
    u16*   buf_bb = buf_zx + (size_t)NROWS * ZXP;                    // 8192 x 64   bf16 (conv'd B)
    u16*   buf_cb = buf_bb + (size_t)NROWS * 64;                     // 8192 x 64   bf16 (conv'd C)
    u16*   buf_ys = buf_cb + (size_t)NROWS * 64;                     // 8192 x 512  bf16
    u16*   buf_S  = buf_ys + (size_t)NROWS * D_INNER;                // 128*8*4096  bf16
    u16*   buf_hb = buf_S  + (size_t)BATCH * NCHUNK * NHEADS * 4096; // 8192 x 256  bf16
    u16*   buf_wi = buf_hb + (size_t)NROWS * D_MODEL;                // 2x1280x256  bf16
    u16*   buf_wo = buf_wi + (size_t)2 * ZXP * D_MODEL;              // 2x256x512   bf16
    float* buf_dt = (float*)(buf_wo + (size_t)2 * D_MODEL * D_INNER);// 8192 x 8    f32
    float* buf_a  = buf_dt + (size_t)NROWS * NHEADS;                 // 64 x 1024   f32

    void* kargs[] = {
        (void*)&x, (void*)&in_proj_w, (void*)&conv_w, (void*)&conv_b,
        (void*)&dt_bias, (void*)&A_log, (void*)&Dp, (void*)&norm_w,
        (void*)&out_proj_w, (void*)&out,
        (void*)&buf_zx, (void*)&buf_bb, (void*)&buf_cb, (void*)&buf_ys,
        (void*)&buf_S, (void*)&buf_hb, (void*)&buf_wi, (void*)&buf_wo,
        (void*)&buf_dt, (void*)&buf_a
    };
    hipLaunchCooperativeKernel((void*)mamba_mega, dim3(256), dim3(512),
                               kargs, 0, stream);
}

// Round 8
// 182.483 us; speedup vs baseline: 3.8166x; 3.8166x over previous
//
#include <hip/hip_runtime.h>
#include <hip/hip_bf16.h>
#include <math.h>

#define D_MODEL   256
#define D_STATE   64
#define D_CONV    4
#define D_INNER   512
#define HEADDIM   64
#define NHEADS    8
#define CONV_DIM  640     // D_INNER + 2*D_STATE
#define D_IN_PROJ 1160    // 2*D_INNER + 2*D_STATE + NHEADS
#define ZXP       1280    // padded in_proj N (10 x 128 tiles)
#define SEQLEN    1024
#define BATCH     8
#define NROWS     8192    // BATCH * SEQLEN
#define EPS       1e-5f
#define CHUNK     64
#define NCHUNK    (SEQLEN / CHUNK)   // 16

typedef __attribute__((ext_vector_type(8))) short bf16x8;
typedef __attribute__((ext_vector_type(4))) short s16x4;
typedef __attribute__((ext_vector_type(8))) unsigned short u16x8;
typedef __attribute__((ext_vector_type(4))) unsigned short u16x4;
typedef __attribute__((ext_vector_type(4))) float f32x4;
typedef unsigned int u32;
typedef unsigned short u16;

__device__ __forceinline__ void cp16(const short* g, short* l) {
    __builtin_amdgcn_global_load_lds((const __attribute__((address_space(1))) u32*)g,
                                     (__attribute__((address_space(3))) u32*)l, 16, 0, 0);
}
__device__ __forceinline__ u16 bfc(float f) {
    union { __hip_bfloat16 h; u16 u; } cv;
    cv.h = __float2bfloat16(f);
    return cv.u;
}
__device__ __forceinline__ float bf2f(u16 u) {
    union { u32 v; float f; } cv;
    cv.v = ((u32)u) << 16;
    return cv.f;
}
__device__ __forceinline__ float silu_f(float a) {
    return a * __builtin_amdgcn_rcpf(1.f + __expf(-a));
}
__device__ __forceinline__ void store_out(float* p, float v) { *p = v; }
__device__ __forceinline__ void store_out(__hip_bfloat16* p, float v) { *p = __float2bfloat16(v); }

// 64-col bf16 LDS tile, XOR-octet swizzle
__device__ __forceinline__ int swz(int row, int col) {
    return row * 64 + (((col & 56) ^ ((row & 7) << 3)) | (col & 7));
}
__device__ __forceinline__ bf16x8 ldfrag(const short* base, int row, int oct) {
    return *(const bf16x8*)&base[row * 64 + ((oct * 8) ^ ((row & 7) * 8))];
}
__device__ __forceinline__ void wr2u(short* base, int row, int col2, u16 a, u16 b) {
    int idx = row * 64 + (((col2 & 56) ^ ((row & 7) << 3)) | (col2 & 6));
    *(u32*)&base[idx] = (u32)a | ((u32)b << 16);
}

// ---------------------------------------------------------------------------
// C[m,n] = A[m,:] . W[n,:]  (bf16, fp32 acc). Tile 128x128, BK=32, 4 waves.
// LDS octet-XOR swizzled (via pre-swizzled GLOBAL source; LDS dest linear):
// row r slot s holds global octet s^(r&3); read octet lq at slot lq^(r&3).
// Cuts the 8-way ds_read_b128 bank conflict of the naive layout to 4-way.
// WITH_DT: spill raw cols [D_IN_PROJ-8, D_IN_PROJ) to fp32 dtout.
// ---------------------------------------------------------------------------
template <typename OUT, bool WITH_DT>
__global__ __launch_bounds__(256) void gemm_mfma(const short* __restrict__ A,
                                                 const short* __restrict__ W,
                                                 OUT* __restrict__ C,
                                                 float* __restrict__ dtout,
                                                 int N, int K, int lda) {
    __shared__ short As[128 * 32];
    __shared__ short Ws[128 * 32];
    const int tid  = threadIdx.x;
    const int m0   = blockIdx.y * 128;
    const int n0   = blockIdx.x * 128;
    const int wave = tid >> 6;
    const int lane = tid & 63;
    const int wm   = (wave & 1) * 64;
    const int wn   = (wave >> 1) * 64;
    const int lm   = lane & 15;
    const int lq   = lane >> 4;

    const int sr   = tid >> 2;
    const int soct = (tid & 3) ^ (sr & 3);       // swizzled source octet
    const short* ga = A + (size_t)(m0 + sr) * lda + soct * 8;
    const short* gw = W + (size_t)(n0 + sr) * K + soct * 8;
    short* la = &As[tid * 8];
    short* lw = &Ws[tid * 8];
    const size_t ga2 = (size_t)64 * lda;         // (sr+64)&3 == sr&3: same soct
    const size_t gw2 = (size_t)64 * K;

    const int oa = (lq ^ (lm & 3)) * 8;          // swizzled read octet offset

    f32x4 acc[4][4] = {};

    for (int k0 = 0; k0 < K; k0 += 32) {
        cp16(ga,       la);
        cp16(ga + ga2, la + 64 * 32);
        cp16(gw,       lw);
        cp16(gw + gw2, lw + 64 * 32);
        ga += 32; gw += 32;
        __syncthreads();
        bf16x8 af[4], bfr[4];
        #pragma unroll
        for (int i = 0; i < 4; i++) {
            af[i]  = *(const bf16x8*)&As[(wm + i * 16 + lm) * 32 + oa];
            bfr[i] = *(const bf16x8*)&Ws[(wn + i * 16 + lm) * 32 + oa];
        }
        #pragma unroll
        for (int i = 0; i < 4; i++)
            #pragma unroll
            for (int j = 0; j < 4; j++)
                acc[i][j] = __builtin_amdgcn_mfma_f32_16x16x32_bf16(af[i], bfr[j], acc[i][j], 0, 0, 0);
        __syncthreads();
    }
    #pragma unroll
    for (int i = 0; i < 4; i++)
        #pragma unroll
        for (int r = 0; r < 4; r++) {
            int m = m0 + wm + i * 16 + lq * 4 + r;
            #pragma unroll
            for (int j = 0; j < 4; j++) {
                int n = n0 + wn + j * 16 + lm;
                float v = acc[i][j][r];
                store_out(&C[(size_t)m * N + n], v);
                if (WITH_DT) {
                    if (n >= D_IN_PROJ - NHEADS && n < D_IN_PROJ)
                        dtout[(size_t)m * NHEADS + (n - (D_IN_PROJ - NHEADS))] = v;
                }
            }
        }
}

// ---------------------------------------------------------------------------
// Fused casts: x -> bf16, in_proj_w -> padded bf16, out_proj_w -> bf16.
// ---------------------------------------------------------------------------
#define NX_C  (NROWS * D_MODEL)
#define NWI_C (2 * ZXP * D_MODEL)
#define NWO_C (2 * D_MODEL * D_INNER)
__global__ __launch_bounds__(256) void cast_all_kernel(
    const float* __restrict__ x, const float* __restrict__ wi,
    const float* __restrict__ wo,
    u16* __restrict__ xb, u16* __restrict__ wib, u16* __restrict__ wob)
{
    int idx = blockIdx.x * 256 + threadIdx.x;
    if (idx < NX_C) { xb[idx] = bfc(x[idx]); return; }
    idx -= NX_C;
    if (idx < NWI_C) {
        int k = idx & 255;
        int rb = idx >> 8;
        int r = rb % ZXP;
        int blk = rb / ZXP;
        float v = (r < D_IN_PROJ)
            ? wi[(size_t)blk * D_IN_PROJ * D_MODEL + (size_t)r * D_MODEL + k] : 0.f;
        wib[idx] = bfc(v);
        return;
    }
    idx -= NWI_C;
    wob[idx] = bfc(wo[idx]);
}

// ---------------------------------------------------------------------------
// Slim depthwise causal conv for B/C channels only (xBC-relative [512,640)).
// ---------------------------------------------------------------------------
__global__ __launch_bounds__(256) void conv_bc_kernel(const u16* __restrict__ zx,
                                                      const float* __restrict__ cw,
                                                      const float* __restrict__ cb,
                                                      u16* __restrict__ Bb,
                                                      u16* __restrict__ Cb) {
    int idx = blockIdx.x * 256 + threadIdx.x;   // (NROWS/4) * 32
    int cc  = 512 + (idx & 31) * 4;             // xBC-relative channel, [512,640)
    int r4  = (idx >> 5) * 4;
    int l4  = r4 & (SEQLEN - 1);
    float wt[4][4];     // [k][tap]
    #pragma unroll
    for (int k = 0; k < 4; k++)
        *(float4*)&wt[k][0] = *(const float4*)&cw[(cc + k) * 4];
    float4 cbv = *(const float4*)&cb[cc];
    float cbk[4] = {cbv.x, cbv.y, cbv.z, cbv.w};

    const u16* base = zx + (size_t)r4 * ZXP + D_INNER + cc;
    u16x4 hrow[7];
    #pragma unroll
    for (int k = 0; k < 3; k++) {
        if (l4 != 0) hrow[k] = *(const u16x4*)&base[(k - 3) * ZXP];
        else { hrow[k][0] = 0; hrow[k][1] = 0; hrow[k][2] = 0; hrow[k][3] = 0; }
    }
    #pragma unroll
    for (int k = 3; k < 7; k++)
        hrow[k] = *(const u16x4*)&base[(k - 3) * ZXP];

    const bool isB = (cc < 512 + D_STATE);
    u16* dst = isB ? (Bb + (size_t)r4 * 64 + (cc - 512))
                   : (Cb + (size_t)r4 * 64 + (cc - 576));
    #pragma unroll
    for (int rr = 0; rr < 4; rr++) {
        u16x4 o;
        #pragma unroll
        for (int k = 0; k < 4; k++) {
            float acc = cbk[k];
            #pragma unroll
            for (int tap = 0; tap < 4; tap++)
                acc = fmaf(bf2f(hrow[rr + tap][k]), wt[k][tap], acc);
            o[k] = bfc(silu_f(acc));
        }
        *(u16x4*)&dst[(size_t)rr * 64] = o;
    }
}

// ---------------------------------------------------------------------------
// SSD intra-chunk, MFMA, with fused x-channel conv+SiLU. One block per
// (b, chunk, head). B/C staged from compact Bb/Cb. D*x folded into ys.
// ---------------------------------------------------------------------------
__global__ __launch_bounds__(256) void ssd_intra_kernel(
    const u16* __restrict__ zx, const u16* __restrict__ Bb,
    const u16* __restrict__ Cbuf,
    const float* __restrict__ dtbuf,
    const float* __restrict__ dt_bias, const float* __restrict__ A_log,
    const float* __restrict__ cw, const float* __restrict__ cb,
    const float* __restrict__ Dp,
    u16* __restrict__ ys, u16* __restrict__ Schunk,
    float* __restrict__ adec)
{
    const int h   = blockIdx.x & 7;
    const int c   = (blockIdx.x >> 3) & 15;
    const int b   = blockIdx.x >> 7;
    const int tid = threadIdx.x;
    const int row0 = b * SEQLEN + c * CHUNK;

    __shared__ short Xt[64 * 64];    // [p][t]
    __shared__ short Bn[64 * 64];    // [t][n]
    __shared__ short Cn[64 * 64];    // [t][n]  -> reused as MT [t][tau]
    __shared__ short BTw[64 * 64];   // [n][t], w-folded
    __shared__ float cums[64], dts_s[64], ws_s[64];
    __shared__ float4 wls[64];       // conv weights for this head's x slice
    __shared__ float  bls[64];

    if (tid < 64) {
        const float A = -__expf(A_log[h] * 1.44269504089f);
        float raw = dtbuf[(size_t)(row0 + tid) * NHEADS + h] + dt_bias[h];
        float dtv = (raw > 20.f) ? raw : log1pf(__expf(raw));
        float v = dtv * A;
        #pragma unroll
        for (int off = 1; off < 64; off <<= 1) {
            float o = __shfl_up(v, off, 64);
            if (tid >= off) v += o;
        }
        float tot = __shfl(v, 63, 64);
        cums[tid]  = v;
        dts_s[tid] = dtv;
        ws_s[tid]  = __expf(tot - v) * dtv;
        adec[(size_t)(b * NHEADS + h) * SEQLEN + c * CHUNK + tid] = __expf(v);
    } else if (tid < 128) {
        int k = tid - 64;                 // 0..63
        int ch = h * HEADDIM + k;         // xBC-relative x channel
        wls[k] = *(const float4*)&cw[ch * 4];
        bls[k] = cb[ch];
    }
    __syncthreads();

    {   // stage B/C from compact buffers; fused conv+SiLU for x from zx
        const int t2 = (tid >> 3) * 2;       // 0..62
        const int c8 = (tid & 7) * 8;        // 0..56
        const int lb = c * CHUNK + t2;       // sequence-local row index
        u16x8 bv0 = *(const u16x8*)&Bb[(size_t)(row0 + t2) * 64 + c8];
        u16x8 bv1 = *(const u16x8*)&Bb[(size_t)(row0 + t2 + 1) * 64 + c8];
        u16x8 cv0 = *(const u16x8*)&Cbuf[(size_t)(row0 + t2) * 64 + c8];
        u16x8 cv1 = *(const u16x8*)&Cbuf[(size_t)(row0 + t2 + 1) * 64 + c8];
        *(u16x8*)&Bn[swz(t2,     c8)] = bv0;
        *(u16x8*)&Bn[swz(t2 + 1, c8)] = bv1;
        *(u16x8*)&Cn[swz(t2,     c8)] = cv0;
        *(u16x8*)&Cn[swz(t2 + 1, c8)] = cv1;
        float w0 = ws_s[t2], w1 = ws_s[t2 + 1];

        const u16* p = zx + (size_t)(row0 + t2) * ZXP + D_INNER + h * HEADDIM + c8;
        u16x8 zz;
        #pragma unroll
        for (int q = 0; q < 8; q++) zz[q] = 0;
        u16x8 r0 = (lb >= 3) ? *(const u16x8*)(p - 3 * ZXP) : zz;
        u16x8 r1 = (lb >= 2) ? *(const u16x8*)(p - 2 * ZXP) : zz;
        u16x8 r2 = (lb >= 1) ? *(const u16x8*)(p - 1 * ZXP) : zz;
        u16x8 r3 = *(const u16x8*)p;
        u16x8 r4 = *(const u16x8*)(p + ZXP);
        #pragma unroll
        for (int k = 0; k < 8; k++) {
            float4 w4  = wls[c8 + k];
            float bias = bls[c8 + k];
            float a0 = bias, a1 = bias;
            a0 = fmaf(bf2f(r0[k]), w4.x, a0);
            a0 = fmaf(bf2f(r1[k]), w4.y, a0);
            a0 = fmaf(bf2f(r2[k]), w4.z, a0);
            a0 = fmaf(bf2f(r3[k]), w4.w, a0);
            a1 = fmaf(bf2f(r1[k]), w4.x, a1);
            a1 = fmaf(bf2f(r2[k]), w4.y, a1);
            a1 = fmaf(bf2f(r3[k]), w4.z, a1);
            a1 = fmaf(bf2f(r4[k]), w4.w, a1);
            wr2u(Xt,  c8 + k, t2, bfc(silu_f(a0)), bfc(silu_f(a1)));
            wr2u(BTw, c8 + k, t2, bfc(bf2f(bv0[k]) * w0), bfc(bf2f(bv1[k]) * w1));
        }
    }
    __syncthreads();

    const int lane = tid & 63, w = tid >> 6;
    const int lm = lane & 15, lq = lane >> 4;
    const int tau0 = 16 * w + lq * 4;

    bf16x8 aG0 = ldfrag(Bn, 16 * w + lm, lq);
    bf16x8 aG1 = ldfrag(Bn, 16 * w + lm, 4 + lq);
    f32x4 g[4] = {};
    #pragma unroll
    for (int j = 0; j < 4; j++) {
        g[j] = __builtin_amdgcn_mfma_f32_16x16x32_bf16(aG0, ldfrag(Cn, 16 * j + lm, lq),     g[j], 0, 0, 0);
        g[j] = __builtin_amdgcn_mfma_f32_16x16x32_bf16(aG1, ldfrag(Cn, 16 * j + lm, 4 + lq), g[j], 0, 0, 0);
    }
    float ctau[4], dtau[4];
    *(float4*)&ctau[0] = *(const float4*)&cums[tau0];
    *(float4*)&dtau[0] = *(const float4*)&dts_s[tau0];
    s16x4 mp[4];
    #pragma unroll
    for (int j = 0; j < 4; j++) {
        int t = 16 * j + lm;
        float ct = cums[t];
        #pragma unroll
        for (int r = 0; r < 4; r++) {
            int tau = tau0 + r;
            float m = (t >= tau) ? g[j][r] * __expf(ct - ctau[r]) * dtau[r] : 0.f;
            mp[j][r] = (short)bfc(m);
        }
    }
    __syncthreads();
    #pragma unroll
    for (int j = 0; j < 4; j++)
        *(s16x4*)&Cn[swz(16 * j + lm, tau0)] = mp[j];   // MT[t][tau]
    __syncthreads();

    bf16x8 aY0 = ldfrag(Cn,  16 * w + lm, lq);
    bf16x8 aY1 = ldfrag(Cn,  16 * w + lm, 4 + lq);
    bf16x8 aS0 = ldfrag(BTw, 16 * w + lm, lq);
    bf16x8 aS1 = ldfrag(BTw, 16 * w + lm, 4 + lq);
    f32x4 yv[4] = {}, sv[4] = {};
    #pragma unroll
    for (int j = 0; j < 4; j++) {
        bf16x8 xf0 = ldfrag(Xt, 16 * j + lm, lq);
        bf16x8 xf1 = ldfrag(Xt, 16 * j + lm, 4 + lq);
        yv[j] = __builtin_amdgcn_mfma_f32_16x16x32_bf16(aY0, xf0, yv[j], 0, 0, 0);
        yv[j] = __builtin_amdgcn_mfma_f32_16x16x32_bf16(aY1, xf1, yv[j], 0, 0, 0);
        sv[j] = __builtin_amdgcn_mfma_f32_16x16x32_bf16(aS0, xf0, sv[j], 0, 0, 0);
        sv[j] = __builtin_amdgcn_mfma_f32_16x16x32_bf16(aS1, xf1, sv[j], 0, 0, 0);
    }
    const float Dh = Dp[h];
    const int mrow = 16 * w + lq * 4;
    #pragma unroll
    for (int j = 0; j < 4; j++)
        #pragma unroll
        for (int r = 0; r < 4; r++) {
            float xv = bf2f((u16)Xt[swz(16 * j + lm, mrow + r)]);
            ys[(size_t)(row0 + mrow + r) * D_INNER + h * HEADDIM + 16 * j + lm]
                = bfc(yv[j][r] + Dh * xv);
        }
    u16* sb = Schunk + (size_t)((b * NCHUNK + c) * NHEADS + h) * 4096;
    #pragma unroll
    for (int j = 0; j < 4; j++)
        #pragma unroll
        for (int r = 0; r < 4; r++)
            sb[(mrow + r) * 64 + 16 * j + lm] = bfc(sv[j][r]);
}

// ---------------------------------------------------------------------------
// Parallel prefix scan over chunk states.
// ---------------------------------------------------------------------------
__global__ __launch_bounds__(256) void ssd_state_scan_kernel(
    u16* __restrict__ Schunk, const float* __restrict__ adec)
{
    const int q  = blockIdx.x & 3;
    const int bh = blockIdx.x >> 2;
    const int b  = bh >> 3, h = bh & 7;
    const int base = q * 1024 + threadIdx.x * 4;

    u16x4 v[NCHUNK];
    float atot[NCHUNK];
    #pragma unroll
    for (int c = 0; c < NCHUNK; c++) {
        v[c] = *(const u16x4*)&Schunk[(size_t)((b * NCHUNK + c) * NHEADS + h) * 4096 + base];
        atot[c] = adec[(size_t)bh * SEQLEN + c * CHUNK + 63];
    }
    float run[4] = {0.f, 0.f, 0.f, 0.f};
    #pragma unroll
    for (int c = 0; c < NCHUNK; c++) {
        u16x4 pv;
        #pragma unroll
        for (int k = 0; k < 4; k++) pv[k] = bfc(run[k]);
        *(u16x4*)&Schunk[(size_t)((b * NCHUNK + c) * NHEADS + h) * 4096 + base] = pv;
        #pragma unroll
        for (int k = 0; k < 4; k++)
            run[k] = fmaf(atot[c], run[k], bf2f(v[c][k]));
    }
}

// ---------------------------------------------------------------------------
// FUSED inter + gate + RMS + out_proj. One block per (b, chunk, 32-row half):
// 256 blocks x 512 threads (8 waves).
// ---------------------------------------------------------------------------
template <typename OUT>
__global__ __launch_bounds__(512) void ssd_finish_proj_kernel(
    const u16* __restrict__ Cb, const u16* __restrict__ zx,
    const u16* __restrict__ ysin, const u16* __restrict__ Schunk,
    const float* __restrict__ adec, const float* __restrict__ nw,
    const u16* __restrict__ wo, OUT* __restrict__ Cout)
{
    const int half = blockIdx.x & 1;
    const int c    = (blockIdx.x >> 1) & 15;
    const int b    = blockIdx.x >> 5;
    const int tid  = threadIdx.x;
    const int row0 = b * SEQLEN + c * CHUNK + half * 32;

    __shared__ short y_lds[32 * 512];    // 32 KB, octet-swizzled
    __shared__ short reg2[256 * 64];     // 32 KB: Ct[32*64]+STs[64*64], later Ws[256*64]
    __shared__ float a_s[256];           // [h][32]
    __shared__ float nw_s[512];
    __shared__ float ps[128];            // [cf4][32]
    __shared__ float scl[32];

    short* Ct  = reg2;
    short* STs = reg2 + 32 * 64;
    short* Ws  = reg2;

    const int lane = tid & 63, w = tid >> 6;
    const int lm = lane & 15, lq = lane >> 4;
    const int rf  = w & 1;       // row-frag (16 rows each)
    const int cf4 = w >> 1;      // 0..3

    nw_s[tid] = nw[tid];
    if (tid < 256) {
        int t2 = tid >> 3, n8 = (tid & 7) * 8;   // Ct stage
        *(u16x8*)&Ct[swz(t2, n8)] = *(const u16x8*)&Cb[(size_t)(row0 + t2) * 64 + n8];
        a_s[tid] = adec[(size_t)(b * NHEADS + (tid >> 5)) * SEQLEN + c * CHUNK + half * 32 + (tid & 31)];
        // STs stage for h=0
        const u16* sb = Schunk + (size_t)((b * NCHUNK + c) * NHEADS) * 4096;
        int n2 = (tid >> 3) * 2, p8 = (tid & 7) * 8;
        u16x8 s0 = *(const u16x8*)&sb[(size_t)n2 * 64 + p8];
        u16x8 s1 = *(const u16x8*)&sb[(size_t)(n2 + 1) * 64 + p8];
        #pragma unroll
        for (int k = 0; k < 8; k++)
            wr2u(STs, p8 + k, n2, s0[k], s1[k]);
    }
    __syncthreads();

    bf16x8 aC0 = ldfrag(Ct, 16 * rf + lm, lq);
    bf16x8 aC1 = ldfrag(Ct, 16 * rf + lm, 4 + lq);
    float ssloc[4] = {0.f, 0.f, 0.f, 0.f};

    for (int h = 0; h < 8; h++) {
        const int n = cf4 * 16 + lm;
        f32x4 U = {};
        U = __builtin_amdgcn_mfma_f32_16x16x32_bf16(aC0, ldfrag(STs, n, lq),     U, 0, 0, 0);
        U = __builtin_amdgcn_mfma_f32_16x16x32_bf16(aC1, ldfrag(STs, n, 4 + lq), U, 0, 0, 0);
        __syncthreads();   // all waves done reading STs(h)
        if (h < 7 && tid < 256) {
            const u16* sb = Schunk + (size_t)((b * NCHUNK + c) * NHEADS + h + 1) * 4096;
            int n2 = (tid >> 3) * 2, p8 = (tid & 7) * 8;
            u16x8 s0 = *(const u16x8*)&sb[(size_t)n2 * 64 + p8];
            u16x8 s1 = *(const u16x8*)&sb[(size_t)(n2 + 1) * 64 + p8];
            #pragma unroll
            for (int k = 0; k < 8; k++)
                wr2u(STs, p8 + k, n2, s0[k], s1[k]);
        }
        {   // epilogue for head h (overlaps STs staging loads)
            const int col = h * 64 + cf4 * 16 + lm;
            const float nwv = nw_s[col];
            #pragma unroll
            for (int r = 0; r < 4; r++) {
                int row = 16 * rf + lq * 4 + r;
                size_t grow = (size_t)(row0 + row);
                float u = U[r] * a_s[h * 32 + row] + bf2f(ysin[grow * D_INNER + col]);
                float zv = bf2f(zx[grow * ZXP + col]);
                float v = u * silu_f(zv);
                ssloc[r] = fmaf(v, v, ssloc[r]);
                y_lds[row * 512 + ((((col >> 3) ^ (row & 7)) << 3) | (col & 7))] = (short)bfc(v * nwv);
            }
        }
        __syncthreads();   // STs(h+1) visible
    }

    // row sum-of-squares -> scl
    #pragma unroll
    for (int r = 0; r < 4; r++) {
        float s = ssloc[r];
        s += __shfl_xor(s, 1, 64); s += __shfl_xor(s, 2, 64);
        s += __shfl_xor(s, 4, 64); s += __shfl_xor(s, 8, 64);
        if (lm == 0) ps[cf4 * 32 + 16 * rf + lq * 4 + r] = s;
    }
    __syncthreads();
    if (tid < 32)
        scl[tid] = rsqrtf((ps[tid] + ps[32 + tid] + ps[64 + tid] + ps[96 + tid])
                          * (1.f / (float)D_INNER) + EPS);
    __syncthreads();

    // out-proj: out[32x256] = y[32x512] @ wo^T, 8 K-slices of 64
    f32x4 acc[4] = {};
    const int arow = 16 * rf + lm;
    for (int kk = 0; kk < 8; kk++) {
        {   // stage wo slice [256][64], source pre-swizzled for ldfrag
            int rr = tid >> 3;          // 0..63
            int oc = tid & 7;
            #pragma unroll
            for (int q = 0; q < 4; q++) {
                int row = rr + q * 64;
                const u16* src = wo + (size_t)row * 512 + kk * 64 + ((oc ^ (row & 7)) * 8);
                cp16((const short*)src, &Ws[q * 4096 + tid * 8]);
            }
        }
        __syncthreads();
        bf16x8 aY0 = *(const bf16x8*)&y_lds[arow * 512 + ((kk * 8) | (lq       ^ (arow & 7))) * 8];
        bf16x8 aY1 = *(const bf16x8*)&y_lds[arow * 512 + ((kk * 8) | ((4 + lq) ^ (arow & 7))) * 8];
        #pragma unroll
        for (int j = 0; j < 4; j++) {
            int n = cf4 * 64 + j * 16 + lm;
            acc[j] = __builtin_amdgcn_mfma_f32_16x16x32_bf16(aY0, ldfrag(Ws, n, lq),     acc[j], 0, 0, 0);
            acc[j] = __builtin_amdgcn_mfma_f32_16x16x32_bf16(aY1, ldfrag(Ws, n, 4 + lq), acc[j], 0, 0, 0);
        }
        __syncthreads();
    }
    const int mrow = 16 * rf + lq * 4;
    #pragma unroll
    for (int r = 0; r < 4; r++) {
        float scale = scl[mrow + r];
        size_t m = (size_t)(row0 + mrow + r);
        #pragma unroll
        for (int j = 0; j < 4; j++) {
            int n = cf4 * 64 + j * 16 + lm;
            store_out(&Cout[m * D_MODEL + n], acc[j][r] * scale);
        }
    }
}

// ---------------------------------------------------------------------------
extern "C" void kernel_launch(void* const* d_in, const int* in_sizes, int n_in,
                              void* d_out, int out_size, void* d_ws, size_t ws_size,
                              hipStream_t stream) {
    const float* x          = (const float*)d_in[0];
    const float* in_proj_w  = (const float*)d_in[1];
    const float* conv_w     = (const float*)d_in[2];
    const float* conv_b     = (const float*)d_in[3];
    const float* dt_bias    = (const float*)d_in[4];
    const float* A_log      = (const float*)d_in[5];
    const float* Dp         = (const float*)d_in[6];
    const float* norm_w     = (const float*)d_in[7];
    const float* out_proj_w = (const float*)d_in[8];
    float* out = (float*)d_out;

    u16*   buf_zx = (u16*)d_ws;                                      // 8192 x 1280 bf16
    u16*   buf_bb = buf_zx + (size_t)NROWS * ZXP;                    // 8192 x 64   bf16 (conv'd B)
    u16*   buf_cb = buf_bb + (size_t)NROWS * 64;                     // 8192 x 64   bf16 (conv'd C)
    u16*   buf_ys = buf_cb + (size_t)NROWS * 64;                     // 8192 x 512  bf16
    u16*   buf_S  = buf_ys + (size_t)NROWS * D_INNER;                // 128*8*4096  bf16
    u16*   buf_hb = buf_S  + (size_t)BATCH * NCHUNK * NHEADS * 4096; // 8192 x 256  bf16
    u16*   buf_wi = buf_hb + (size_t)NROWS * D_MODEL;                // 2x1280x256  bf16
    u16*   buf_wo = buf_wi + (size_t)2 * ZXP * D_MODEL;              // 2x256x512   bf16
    float* buf_dt = (float*)(buf_wo + (size_t)2 * D_MODEL * D_INNER);// 8192 x 8    f32
    float* buf_a  = buf_dt + (size_t)NROWS * NHEADS;                 // 64 x 1024   f32

    cast_all_kernel<<<(NX_C + NWI_C + NWO_C) / 256, 256, 0, stream>>>(
        x, in_proj_w, out_proj_w, buf_hb, buf_wi, buf_wo);

    for (int i = 0; i < 2; i++) {
        gemm_mfma<__hip_bfloat16, true><<<dim3(ZXP / 128, NROWS / 128), 256, 0, stream>>>(
            (const short*)buf_hb, (const short*)(buf_wi + (size_t)i * ZXP * D_MODEL),
            (__hip_bfloat16*)buf_zx, buf_dt, ZXP, D_MODEL, D_MODEL);

        conv_bc_kernel<<<(NROWS / 4) * 32 / 256, 256, 0, stream>>>(
            buf_zx, conv_w + (size_t)i * CONV_DIM * D_CONV,
            conv_b + (size_t)i * CONV_DIM, buf_bb, buf_cb);

        ssd_intra_kernel<<<BATCH * NCHUNK * NHEADS, 256, 0, stream>>>(
            buf_zx, buf_bb, buf_cb, buf_dt,
            dt_bias + i * NHEADS, A_log + i * NHEADS,
            conv_w + (size_t)i * CONV_DIM * D_CONV, conv_b + (size_t)i * CONV_DIM,
            Dp + i * NHEADS, buf_ys, buf_S, buf_a);

        ssd_state_scan_kernel<<<BATCH * NHEADS * 4, 256, 0, stream>>>(buf_S, buf_a);

        if (i == 0) {
            ssd_finish_proj_kernel<__hip_bfloat16><<<BATCH * NCHUNK * 2, 512, 0, stream>>>(
                buf_cb, buf_zx, buf_ys, buf_S, buf_a,
                norm_w, (const u16*)buf_wo, (__hip_bfloat16*)buf_hb);
        } else {
            ssd_finish_proj_kernel<float><<<BATCH * NCHUNK * 2, 512, 0, stream>>>(
                buf_cb, buf_zx, buf_ys, buf_S, buf_a,
                norm_w + D_INNER, (const u16*)(buf_wo + (size_t)D_MODEL * D_INNER), out);
        }
    }
}

// Round 9
// 178.311 us; speedup vs baseline: 3.9059x; 1.0234x over previous
//
#include <hip/hip_runtime.h>
#include <hip/hip_bf16.h>
#include <math.h>

#define D_MODEL   256
#define D_STATE   64
#define D_CONV    4
#define D_INNER   512
#define HEADDIM   64
#define NHEADS    8
#define CONV_DIM  640     // D_INNER + 2*D_STATE
#define D_IN_PROJ 1160    // 2*D_INNER + 2*D_STATE + NHEADS
#define ZXP       1280    // padded in_proj N (10 x 128 tiles)
#define SEQLEN    1024
#define BATCH     8
#define NROWS     8192    // BATCH * SEQLEN
#define EPS       1e-5f
#define CHUNK     64
#define NCHUNK    (SEQLEN / CHUNK)   // 16

typedef __attribute__((ext_vector_type(8))) short bf16x8;
typedef __attribute__((ext_vector_type(4))) short s16x4;
typedef __attribute__((ext_vector_type(8))) unsigned short u16x8;
typedef __attribute__((ext_vector_type(4))) unsigned short u16x4;
typedef __attribute__((ext_vector_type(4))) float f32x4;
typedef unsigned int u32;
typedef unsigned short u16;

__device__ __forceinline__ void cp16(const short* g, short* l) {
    __builtin_amdgcn_global_load_lds((const __attribute__((address_space(1))) u32*)g,
                                     (__attribute__((address_space(3))) u32*)l, 16, 0, 0);
}
__device__ __forceinline__ u16 bfc(float f) {
    union { __hip_bfloat16 h; u16 u; } cv;
    cv.h = __float2bfloat16(f);
    return cv.u;
}
__device__ __forceinline__ float bf2f(u16 u) {
    union { u32 v; float f; } cv;
    cv.v = ((u32)u) << 16;
    return cv.f;
}
__device__ __forceinline__ float silu_f(float a) {
    return a * __builtin_amdgcn_rcpf(1.f + __expf(-a));
}
__device__ __forceinline__ void store_out(float* p, float v) { *p = v; }
__device__ __forceinline__ void store_out(__hip_bfloat16* p, float v) { *p = __float2bfloat16(v); }

// 64-col bf16 LDS tile, XOR-octet swizzle
__device__ __forceinline__ int swz(int row, int col) {
    return row * 64 + (((col & 56) ^ ((row & 7) << 3)) | (col & 7));
}
__device__ __forceinline__ bf16x8 ldfrag(const short* base, int row, int oct) {
    return *(const bf16x8*)&base[row * 64 + ((oct * 8) ^ ((row & 7) * 8))];
}
__device__ __forceinline__ void wr2u(short* base, int row, int col2, u16 a, u16 b) {
    int idx = row * 64 + (((col2 & 56) ^ ((row & 7) << 3)) | (col2 & 6));
    *(u32*)&base[idx] = (u32)a | ((u32)b << 16);
}

// ---------------------------------------------------------------------------
// C[m,n] = A[m,:] . W[n,:]  (bf16, fp32 acc). Tile 128x128, BK=32, 4 waves.
// LDS octet-XOR swizzled (via pre-swizzled GLOBAL source; LDS dest linear).
// WITH_DT: spill raw cols [D_IN_PROJ-8, D_IN_PROJ) to fp32 dtout.
// ---------------------------------------------------------------------------
template <typename OUT, bool WITH_DT>
__global__ __launch_bounds__(256) void gemm_mfma(const short* __restrict__ A,
                                                 const short* __restrict__ W,
                                                 OUT* __restrict__ C,
                                                 float* __restrict__ dtout,
                                                 int N, int K, int lda) {
    __shared__ short As[128 * 32];
    __shared__ short Ws[128 * 32];
    const int tid  = threadIdx.x;
    const int m0   = blockIdx.y * 128;
    const int n0   = blockIdx.x * 128;
    const int wave = tid >> 6;
    const int lane = tid & 63;
    const int wm   = (wave & 1) * 64;
    const int wn   = (wave >> 1) * 64;
    const int lm   = lane & 15;
    const int lq   = lane >> 4;

    const int sr   = tid >> 2;
    const int soct = (tid & 3) ^ (sr & 3);       // swizzled source octet
    const short* ga = A + (size_t)(m0 + sr) * lda + soct * 8;
    const short* gw = W + (size_t)(n0 + sr) * K + soct * 8;
    short* la = &As[tid * 8];
    short* lw = &Ws[tid * 8];
    const size_t ga2 = (size_t)64 * lda;         // (sr+64)&3 == sr&3: same soct
    const size_t gw2 = (size_t)64 * K;

    const int oa = (lq ^ (lm & 3)) * 8;          // swizzled read octet offset

    f32x4 acc[4][4] = {};

    for (int k0 = 0; k0 < K; k0 += 32) {
        cp16(ga,       la);
        cp16(ga + ga2, la + 64 * 32);
        cp16(gw,       lw);
        cp16(gw + gw2, lw + 64 * 32);
        ga += 32; gw += 32;
        __syncthreads();
        bf16x8 af[4], bfr[4];
        #pragma unroll
        for (int i = 0; i < 4; i++) {
            af[i]  = *(const bf16x8*)&As[(wm + i * 16 + lm) * 32 + oa];
            bfr[i] = *(const bf16x8*)&Ws[(wn + i * 16 + lm) * 32 + oa];
        }
        #pragma unroll
        for (int i = 0; i < 4; i++)
            #pragma unroll
            for (int j = 0; j < 4; j++)
                acc[i][j] = __builtin_amdgcn_mfma_f32_16x16x32_bf16(af[i], bfr[j], acc[i][j], 0, 0, 0);
        __syncthreads();
    }
    #pragma unroll
    for (int i = 0; i < 4; i++)
        #pragma unroll
        for (int r = 0; r < 4; r++) {
            int m = m0 + wm + i * 16 + lq * 4 + r;
            #pragma unroll
            for (int j = 0; j < 4; j++) {
                int n = n0 + wn + j * 16 + lm;
                float v = acc[i][j][r];
                store_out(&C[(size_t)m * N + n], v);
                if (WITH_DT) {
                    if (n >= D_IN_PROJ - NHEADS && n < D_IN_PROJ)
                        dtout[(size_t)m * NHEADS + (n - (D_IN_PROJ - NHEADS))] = v;
                }
            }
        }
}

// ---------------------------------------------------------------------------
// Fused casts: x -> bf16, in_proj_w -> padded bf16, out_proj_w -> bf16.
// ---------------------------------------------------------------------------
#define NX_C  (NROWS * D_MODEL)
#define NWI_C (2 * ZXP * D_MODEL)
#define NWO_C (2 * D_MODEL * D_INNER)
__global__ __launch_bounds__(256) void cast_all_kernel(
    const float* __restrict__ x, const float* __restrict__ wi,
    const float* __restrict__ wo,
    u16* __restrict__ xb, u16* __restrict__ wib, u16* __restrict__ wob)
{
    int idx = blockIdx.x * 256 + threadIdx.x;
    if (idx < NX_C) { xb[idx] = bfc(x[idx]); return; }
    idx -= NX_C;
    if (idx < NWI_C) {
        int k = idx & 255;
        int rb = idx >> 8;
        int r = rb % ZXP;
        int blk = rb / ZXP;
        float v = (r < D_IN_PROJ)
            ? wi[(size_t)blk * D_IN_PROJ * D_MODEL + (size_t)r * D_MODEL + k] : 0.f;
        wib[idx] = bfc(v);
        return;
    }
    idx -= NWI_C;
    wob[idx] = bfc(wo[idx]);
}

// ---------------------------------------------------------------------------
// SSD intra-chunk, MFMA, with FULLY fused depthwise conv+SiLU (x slice + B +
// C) staged straight from zx with 3-row causal halo. One block per
// (b, chunk, head); B/C conv redundant 8x (tiny: ~128 FMA/thread) which
// buys deletion of the conv kernel + its launch boundary. h==0 block writes
// compact conv'd C rows to Cb for finish. D*x folded into ys.
// ---------------------------------------------------------------------------
__global__ __launch_bounds__(256) void ssd_intra_kernel(
    const u16* __restrict__ zx,
    const float* __restrict__ dtbuf,
    const float* __restrict__ dt_bias, const float* __restrict__ A_log,
    const float* __restrict__ cw, const float* __restrict__ cb,
    const float* __restrict__ Dp,
    u16* __restrict__ ys, u16* __restrict__ Schunk,
    float* __restrict__ adec, u16* __restrict__ Cb)
{
    const int h   = blockIdx.x & 7;
    const int c   = (blockIdx.x >> 3) & 15;
    const int b   = blockIdx.x >> 7;
    const int tid = threadIdx.x;
    const int row0 = b * SEQLEN + c * CHUNK;

    __shared__ short Xt[64 * 64];    // [p][t]
    __shared__ short Bn[64 * 64];    // [t][n]
    __shared__ short Cn[64 * 64];    // [t][n]  -> reused as MT [t][tau]
    __shared__ short BTw[64 * 64];   // [n][t], w-folded
    __shared__ float cums[64], dts_s[64], ws_s[64];
    __shared__ float4 wls[192];      // conv weights: [g*64+k]; g=0 x, 1 B, 2 C
    __shared__ float  bls[192];

    if (tid < 64) {
        const float A = -__expf(A_log[h] * 1.44269504089f);
        float raw = dtbuf[(size_t)(row0 + tid) * NHEADS + h] + dt_bias[h];
        float dtv = (raw > 20.f) ? raw : log1pf(__expf(raw));
        float v = dtv * A;
        #pragma unroll
        for (int off = 1; off < 64; off <<= 1) {
            float o = __shfl_up(v, off, 64);
            if (tid >= off) v += o;
        }
        float tot = __shfl(v, 63, 64);
        cums[tid]  = v;
        dts_s[tid] = dtv;
        ws_s[tid]  = __expf(tot - v) * dtv;
        adec[(size_t)(b * NHEADS + h) * SEQLEN + c * CHUNK + tid] = __expf(v);
    } else {
        int wi = tid - 64;               // 0..191
        int g = wi >> 6, k = wi & 63;
        int ch = (g == 0) ? h * HEADDIM + k : (g == 1 ? 512 + k : 576 + k);
        wls[wi] = *(const float4*)&cw[ch * 4];
        bls[wi] = cb[ch];
    }
    __syncthreads();

    {   // fused conv+SiLU staging for x (head slice), B, C from zx
        const int t2 = (tid >> 3) * 2;       // 0..62
        const int c8 = (tid & 7) * 8;        // 0..56
        const int lb = c * CHUNK + t2;       // sequence-local row index
        const u16* zb = zx + (size_t)(row0 + t2) * ZXP + D_INNER;
        const float w0 = ws_s[t2], w1 = ws_s[t2 + 1];
        u16x8 zz;
        #pragma unroll
        for (int q = 0; q < 8; q++) zz[q] = 0;

        #pragma unroll
        for (int g = 0; g < 3; g++) {
            const int gc = (g == 0) ? h * HEADDIM + c8 : (g == 1 ? 512 + c8 : 576 + c8);
            const u16* p = zb + gc;
            u16x8 r0 = (lb >= 3) ? *(const u16x8*)(p - 3 * ZXP) : zz;
            u16x8 r1 = (lb >= 2) ? *(const u16x8*)(p - 2 * ZXP) : zz;
            u16x8 r2 = (lb >= 1) ? *(const u16x8*)(p - 1 * ZXP) : zz;
            u16x8 r3 = *(const u16x8*)p;
            u16x8 r4 = *(const u16x8*)(p + ZXP);
            u16x8 o0, o1;
            #pragma unroll
            for (int k = 0; k < 8; k++) {
                float4 w4  = wls[g * 64 + c8 + k];
                float bias = bls[g * 64 + c8 + k];
                float a0 = bias, a1 = bias;
                a0 = fmaf(bf2f(r0[k]), w4.x, a0);
                a0 = fmaf(bf2f(r1[k]), w4.y, a0);
                a0 = fmaf(bf2f(r2[k]), w4.z, a0);
                a0 = fmaf(bf2f(r3[k]), w4.w, a0);
                a1 = fmaf(bf2f(r1[k]), w4.x, a1);
                a1 = fmaf(bf2f(r2[k]), w4.y, a1);
                a1 = fmaf(bf2f(r3[k]), w4.z, a1);
                a1 = fmaf(bf2f(r4[k]), w4.w, a1);
                float s0 = silu_f(a0);
                float s1 = silu_f(a1);
                if (g == 0) {
                    wr2u(Xt, c8 + k, t2, bfc(s0), bfc(s1));
                } else if (g == 1) {
                    o0[k] = bfc(s0); o1[k] = bfc(s1);
                    wr2u(BTw, c8 + k, t2, bfc(s0 * w0), bfc(s1 * w1));
                } else {
                    o0[k] = bfc(s0); o1[k] = bfc(s1);
                }
            }
            if (g == 1) {
                *(u16x8*)&Bn[swz(t2,     c8)] = o0;
                *(u16x8*)&Bn[swz(t2 + 1, c8)] = o1;
            } else if (g == 2) {
                *(u16x8*)&Cn[swz(t2,     c8)] = o0;
                *(u16x8*)&Cn[swz(t2 + 1, c8)] = o1;
                if (h == 0) {
                    *(u16x8*)&Cb[(size_t)(row0 + t2)     * 64 + c8] = o0;
                    *(u16x8*)&Cb[(size_t)(row0 + t2 + 1) * 64 + c8] = o1;
                }
            }
        }
    }
    __syncthreads();

    const int lane = tid & 63, w = tid >> 6;
    const int lm = lane & 15, lq = lane >> 4;
    const int tau0 = 16 * w + lq * 4;

    bf16x8 aG0 = ldfrag(Bn, 16 * w + lm, lq);
    bf16x8 aG1 = ldfrag(Bn, 16 * w + lm, 4 + lq);
    f32x4 g[4] = {};
    #pragma unroll
    for (int j = 0; j < 4; j++) {
        g[j] = __builtin_amdgcn_mfma_f32_16x16x32_bf16(aG0, ldfrag(Cn, 16 * j + lm, lq),     g[j], 0, 0, 0);
        g[j] = __builtin_amdgcn_mfma_f32_16x16x32_bf16(aG1, ldfrag(Cn, 16 * j + lm, 4 + lq), g[j], 0, 0, 0);
    }
    float ctau[4], dtau[4];
    *(float4*)&ctau[0] = *(const float4*)&cums[tau0];
    *(float4*)&dtau[0] = *(const float4*)&dts_s[tau0];
    s16x4 mp[4];
    #pragma unroll
    for (int j = 0; j < 4; j++) {
        int t = 16 * j + lm;
        float ct = cums[t];
        #pragma unroll
        for (int r = 0; r < 4; r++) {
            int tau = tau0 + r;
            float m = (t >= tau) ? g[j][r] * __expf(ct - ctau[r]) * dtau[r] : 0.f;
            mp[j][r] = (short)bfc(m);
        }
    }
    __syncthreads();
    #pragma unroll
    for (int j = 0; j < 4; j++)
        *(s16x4*)&Cn[swz(16 * j + lm, tau0)] = mp[j];   // MT[t][tau]
    __syncthreads();

    bf16x8 aY0 = ldfrag(Cn,  16 * w + lm, lq);
    bf16x8 aY1 = ldfrag(Cn,  16 * w + lm, 4 + lq);
    bf16x8 aS0 = ldfrag(BTw, 16 * w + lm, lq);
    bf16x8 aS1 = ldfrag(BTw, 16 * w + lm, 4 + lq);
    f32x4 yv[4] = {}, sv[4] = {};
    #pragma unroll
    for (int j = 0; j < 4; j++) {
        bf16x8 xf0 = ldfrag(Xt, 16 * j + lm, lq);
        bf16x8 xf1 = ldfrag(Xt, 16 * j + lm, 4 + lq);
        yv[j] = __builtin_amdgcn_mfma_f32_16x16x32_bf16(aY0, xf0, yv[j], 0, 0, 0);
        yv[j] = __builtin_amdgcn_mfma_f32_16x16x32_bf16(aY1, xf1, yv[j], 0, 0, 0);
        sv[j] = __builtin_amdgcn_mfma_f32_16x16x32_bf16(aS0, xf0, sv[j], 0, 0, 0);
        sv[j] = __builtin_amdgcn_mfma_f32_16x16x32_bf16(aS1, xf1, sv[j], 0, 0, 0);
    }
    const float Dh = Dp[h];
    const int mrow = 16 * w + lq * 4;
    #pragma unroll
    for (int j = 0; j < 4; j++)
        #pragma unroll
        for (int r = 0; r < 4; r++) {
            float xv = bf2f((u16)Xt[swz(16 * j + lm, mrow + r)]);
            ys[(size_t)(row0 + mrow + r) * D_INNER + h * HEADDIM + 16 * j + lm]
                = bfc(yv[j][r] + Dh * xv);
        }
    u16* sb = Schunk + (size_t)((b * NCHUNK + c) * NHEADS + h) * 4096;
    #pragma unroll
    for (int j = 0; j < 4; j++)
        #pragma unroll
        for (int r = 0; r < 4; r++)
            sb[(mrow + r) * 64 + 16 * j + lm] = bfc(sv[j][r]);
}

// ---------------------------------------------------------------------------
// Parallel prefix scan over chunk states.
// ---------------------------------------------------------------------------
__global__ __launch_bounds__(256) void ssd_state_scan_kernel(
    u16* __restrict__ Schunk, const float* __restrict__ adec)
{
    const int q  = blockIdx.x & 3;
    const int bh = blockIdx.x >> 2;
    const int b  = bh >> 3, h = bh & 7;
    const int base = q * 1024 + threadIdx.x * 4;

    u16x4 v[NCHUNK];
    float atot[NCHUNK];
    #pragma unroll
    for (int c = 0; c < NCHUNK; c++) {
        v[c] = *(const u16x4*)&Schunk[(size_t)((b * NCHUNK + c) * NHEADS + h) * 4096 + base];
        atot[c] = adec[(size_t)bh * SEQLEN + c * CHUNK + 63];
    }
    float run[4] = {0.f, 0.f, 0.f, 0.f};
    #pragma unroll
    for (int c = 0; c < NCHUNK; c++) {
        u16x4 pv;
        #pragma unroll
        for (int k = 0; k < 4; k++) pv[k] = bfc(run[k]);
        *(u16x4*)&Schunk[(size_t)((b * NCHUNK + c) * NHEADS + h) * 4096 + base] = pv;
        #pragma unroll
        for (int k = 0; k < 4; k++)
            run[k] = fmaf(atot[c], run[k], bf2f(v[c][k]));
    }
}

// ---------------------------------------------------------------------------
// FUSED inter + gate + RMS + out_proj. One block per (b, chunk, 32-row half):
// 256 blocks x 512 threads (8 waves).
// ---------------------------------------------------------------------------
template <typename OUT>
__global__ __launch_bounds__(512) void ssd_finish_proj_kernel(
    const u16* __restrict__ Cb, const u16* __restrict__ zx,
    const u16* __restrict__ ysin, const u16* __restrict__ Schunk,
    const float* __restrict__ adec, const float* __restrict__ nw,
    const u16* __restrict__ wo, OUT* __restrict__ Cout)
{
    const int half = blockIdx.x & 1;
    const int c    = (blockIdx.x >> 1) & 15;
    const int b    = blockIdx.x >> 5;
    const int tid  = threadIdx.x;
    const int row0 = b * SEQLEN + c * CHUNK + half * 32;

    __shared__ short y_lds[32 * 512];    // 32 KB, octet-swizzled
    __shared__ short reg2[256 * 64];     // 32 KB: Ct[32*64]+STs[64*64], later Ws[256*64]
    __shared__ float a_s[256];           // [h][32]
    __shared__ float nw_s[512];
    __shared__ float ps[128];            // [cf4][32]
    __shared__ float scl[32];

    short* Ct  = reg2;
    short* STs = reg2 + 32 * 64;
    short* Ws  = reg2;

    const int lane = tid & 63, w = tid >> 6;
    const int lm = lane & 15, lq = lane >> 4;
    const int rf  = w & 1;       // row-frag (16 rows each)
    const int cf4 = w >> 1;      // 0..3

    nw_s[tid] = nw[tid];
    if (tid < 256) {
        int t2 = tid >> 3, n8 = (tid & 7) * 8;   // Ct stage
        *(u16x8*)&Ct[swz(t2, n8)] = *(const u16x8*)&Cb[(size_t)(row0 + t2) * 64 + n8];
        a_s[tid] = adec[(size_t)(b * NHEADS + (tid >> 5)) * SEQLEN + c * CHUNK + half * 32 + (tid & 31)];
        // STs stage for h=0
        const u16* sb = Schunk + (size_t)((b * NCHUNK + c) * NHEADS) * 4096;
        int n2 = (tid >> 3) * 2, p8 = (tid & 7) * 8;
        u16x8 s0 = *(const u16x8*)&sb[(size_t)n2 * 64 + p8];
        u16x8 s1 = *(const u16x8*)&sb[(size_t)(n2 + 1) * 64 + p8];
        #pragma unroll
        for (int k = 0; k < 8; k++)
            wr2u(STs, p8 + k, n2, s0[k], s1[k]);
    }
    __syncthreads();

    bf16x8 aC0 = ldfrag(Ct, 16 * rf + lm, lq);
    bf16x8 aC1 = ldfrag(Ct, 16 * rf + lm, 4 + lq);
    float ssloc[4] = {0.f, 0.f, 0.f, 0.f};

    for (int h = 0; h < 8; h++) {
        const int n = cf4 * 16 + lm;
        f32x4 U = {};
        U = __builtin_amdgcn_mfma_f32_16x16x32_bf16(aC0, ldfrag(STs, n, lq),     U, 0, 0, 0);
        U = __builtin_amdgcn_mfma_f32_16x16x32_bf16(aC1, ldfrag(STs, n, 4 + lq), U, 0, 0, 0);
        __syncthreads();   // all waves done reading STs(h)
        if (h < 7 && tid < 256) {
            const u16* sb = Schunk + (size_t)((b * NCHUNK + c) * NHEADS + h + 1) * 4096;
            int n2 = (tid >> 3) * 2, p8 = (tid & 7) * 8;
            u16x8 s0 = *(const u16x8*)&sb[(size_t)n2 * 64 + p8];
            u16x8 s1 = *(const u16x8*)&sb[(size_t)(n2 + 1) * 64 + p8];
            #pragma unroll
            for (int k = 0; k < 8; k++)
                wr2u(STs, p8 + k, n2, s0[k], s1[k]);
        }
        {   // epilogue for head h (overlaps STs staging loads)
            const int col = h * 64 + cf4 * 16 + lm;
            const float nwv = nw_s[col];
            #pragma unroll
            for (int r = 0; r < 4; r++) {
                int row = 16 * rf + lq * 4 + r;
                size_t grow = (size_t)(row0 + row);
                float u = U[r] * a_s[h * 32 + row] + bf2f(ysin[grow * D_INNER + col]);
                float zv = bf2f(zx[grow * ZXP + col]);
                float v = u * silu_f(zv);
                ssloc[r] = fmaf(v, v, ssloc[r]);
                y_lds[row * 512 + ((((col >> 3) ^ (row & 7)) << 3) | (col & 7))] = (short)bfc(v * nwv);
            }
        }
        __syncthreads();   // STs(h+1) visible
    }

    // row sum-of-squares -> scl
    #pragma unroll
    for (int r = 0; r < 4; r++) {
        float s = ssloc[r];
        s += __shfl_xor(s, 1, 64); s += __shfl_xor(s, 2, 64);
        s += __shfl_xor(s, 4, 64); s += __shfl_xor(s, 8, 64);
        if (lm == 0) ps[cf4 * 32 + 16 * rf + lq * 4 + r] = s;
    }
    __syncthreads();
    if (tid < 32)
        scl[tid] = rsqrtf((ps[tid] + ps[32 + tid] + ps[64 + tid] + ps[96 + tid])
                          * (1.f / (float)D_INNER) + EPS);
    __syncthreads();

    // out-proj: out[32x256] = y[32x512] @ wo^T, 8 K-slices of 64
    f32x4 acc[4] = {};
    const int arow = 16 * rf + lm;
    for (int kk = 0; kk < 8; kk++) {
        {   // stage wo slice [256][64], source pre-swizzled for ldfrag
            int rr = tid >> 3;          // 0..63
            int oc = tid & 7;
            #pragma unroll
            for (int q = 0; q < 4; q++) {
                int row = rr + q * 64;
                const u16* src = wo + (size_t)row * 512 + kk * 64 + ((oc ^ (row & 7)) * 8);
                cp16((const short*)src, &Ws[q * 4096 + tid * 8]);
            }
        }
        __syncthreads();
        bf16x8 aY0 = *(const bf16x8*)&y_lds[arow * 512 + ((kk * 8) | (lq       ^ (arow & 7))) * 8];
        bf16x8 aY1 = *(const bf16x8*)&y_lds[arow * 512 + ((kk * 8) | ((4 + lq) ^ (arow & 7))) * 8];
        #pragma unroll
        for (int j = 0; j < 4; j++) {
            int n = cf4 * 64 + j * 16 + lm;
            acc[j] = __builtin_amdgcn_mfma_f32_16x16x32_bf16(aY0, ldfrag(Ws, n, lq),     acc[j], 0, 0, 0);
            acc[j] = __builtin_amdgcn_mfma_f32_16x16x32_bf16(aY1, ldfrag(Ws, n, 4 + lq), acc[j], 0, 0, 0);
        }
        __syncthreads();
    }
    const int mrow = 16 * rf + lq * 4;
    #pragma unroll
    for (int r = 0; r < 4; r++) {
        float scale = scl[mrow + r];
        size_t m = (size_t)(row0 + mrow + r);
        #pragma unroll
        for (int j = 0; j < 4; j++) {
            int n = cf4 * 64 + j * 16 + lm;
            store_out(&Cout[m * D_MODEL + n], acc[j][r] * scale);
        }
    }
}

// ---------------------------------------------------------------------------
extern "C" void kernel_launch(void* const* d_in, const int* in_sizes, int n_in,
                              void* d_out, int out_size, void* d_ws, size_t ws_size,
                              hipStream_t stream) {
    const float* x          = (const float*)d_in[0];
    const float* in_proj_w  = (const float*)d_in[1];
    const float* conv_w     = (const float*)d_in[2];
    const float* conv_b     = (const float*)d_in[3];
    const float* dt_bias    = (const float*)d_in[4];
    const float* A_log      = (const float*)d_in[5];
    const float* Dp         = (const float*)d_in[6];
    const float* norm_w     = (const float*)d_in[7];
    const float* out_proj_w = (const float*)d_in[8];
    float* out = (float*)d_out;

    u16*   buf_zx = (u16*)d_ws;                                      // 8192 x 1280 bf16
    u16*   buf_cb = buf_zx + (size_t)NROWS * ZXP;                    // 8192 x 64   bf16 (conv'd C)
    u16*   buf_ys = buf_cb + (size_t)NROWS * 64;                     // 8192 x 512  bf16
    u16*   buf_S  = buf_ys + (size_t)NROWS * D_INNER;                // 128*8*4096  bf16
    u16*   buf_hb = buf_S  + (size_t)BATCH * NCHUNK * NHEADS * 4096; // 8192 x 256  bf16
    u16*   buf_wi = buf_hb + (size_t)NROWS * D_MODEL;                // 2x1280x256  bf16
    u16*   buf_wo = buf_wi + (size_t)2 * ZXP * D_MODEL;              // 2x256x512   bf16
    float* buf_dt = (float*)(buf_wo + (size_t)2 * D_MODEL * D_INNER);// 8192 x 8    f32
    float* buf_a  = buf_dt + (size_t)NROWS * NHEADS;                 // 64 x 1024   f32

    cast_all_kernel<<<(NX_C + NWI_C + NWO_C) / 256, 256, 0, stream>>>(
        x, in_proj_w, out_proj_w, buf_hb, buf_wi, buf_wo);

    for (int i = 0; i < 2; i++) {
        gemm_mfma<__hip_bfloat16, true><<<dim3(ZXP / 128, NROWS / 128), 256, 0, stream>>>(
            (const short*)buf_hb, (const short*)(buf_wi + (size_t)i * ZXP * D_MODEL),
            (__hip_bfloat16*)buf_zx, buf_dt, ZXP, D_MODEL, D_MODEL);

        ssd_intra_kernel<<<BATCH * NCHUNK * NHEADS, 256, 0, stream>>>(
            buf_zx, buf_dt,
            dt_bias + i * NHEADS, A_log + i * NHEADS,
            conv_w + (size_t)i * CONV_DIM * D_CONV, conv_b + (size_t)i * CONV_DIM,
            Dp + i * NHEADS, buf_ys, buf_S, buf_a, buf_cb);

        ssd_state_scan_kernel<<<BATCH * NHEADS * 4, 256, 0, stream>>>(buf_S, buf_a);

        if (i == 0) {
            ssd_finish_proj_kernel<__hip_bfloat16><<<BATCH * NCHUNK * 2, 512, 0, stream>>>(
                buf_cb, buf_zx, buf_ys, buf_S, buf_a,
                norm_w, (const u16*)buf_wo, (__hip_bfloat16*)buf_hb);
        } else {
            ssd_finish_proj_kernel<float><<<BATCH * NCHUNK * 2, 512, 0, stream>>>(
                buf_cb, buf_zx, buf_ys, buf_S, buf_a,
                norm_w + D_INNER, (const u16*)(buf_wo + (size_t)D_MODEL * D_INNER), out);
        }
    }
}

// Round 10
// 174.155 us; speedup vs baseline: 3.9991x; 1.0239x over previous
//
#include <hip/hip_runtime.h>
#include <hip/hip_bf16.h>
#include <math.h>

#define D_MODEL   256
#define D_STATE   64
#define D_CONV    4
#define D_INNER   512
#define HEADDIM   64
#define NHEADS    8
#define CONV_DIM  640     // D_INNER + 2*D_STATE
#define D_IN_PROJ 1160    // 2*D_INNER + 2*D_STATE + NHEADS
#define ZXP       1280    // padded in_proj N (10 x 128 tiles)
#define SEQLEN    1024
#define BATCH     8
#define NROWS     8192    // BATCH * SEQLEN
#define EPS       1e-5f
#define CHUNK     64
#define NCHUNK    (SEQLEN / CHUNK)   // 16

typedef __attribute__((ext_vector_type(8))) short bf16x8;
typedef __attribute__((ext_vector_type(4))) short s16x4;
typedef __attribute__((ext_vector_type(8))) unsigned short u16x8;
typedef __attribute__((ext_vector_type(4))) unsigned short u16x4;
typedef __attribute__((ext_vector_type(4))) float f32x4;
typedef unsigned int u32;
typedef unsigned short u16;

__device__ __forceinline__ void cp16(const short* g, short* l) {
    __builtin_amdgcn_global_load_lds((const __attribute__((address_space(1))) u32*)g,
                                     (__attribute__((address_space(3))) u32*)l, 16, 0, 0);
}
__device__ __forceinline__ u16 bfc(float f) {
    union { __hip_bfloat16 h; u16 u; } cv;
    cv.h = __float2bfloat16(f);
    return cv.u;
}
__device__ __forceinline__ float bf2f(u16 u) {
    union { u32 v; float f; } cv;
    cv.v = ((u32)u) << 16;
    return cv.f;
}
__device__ __forceinline__ float silu_f(float a) {
    return a * __builtin_amdgcn_rcpf(1.f + __expf(-a));
}
__device__ __forceinline__ void store_out(float* p, float v) { *p = v; }
__device__ __forceinline__ void store_out(__hip_bfloat16* p, float v) { *p = __float2bfloat16(v); }

// 64-col bf16 LDS tile, XOR-octet swizzle
__device__ __forceinline__ int swz(int row, int col) {
    return row * 64 + (((col & 56) ^ ((row & 7) << 3)) | (col & 7));
}
__device__ __forceinline__ bf16x8 ldfrag(const short* base, int row, int oct) {
    return *(const bf16x8*)&base[row * 64 + ((oct * 8) ^ ((row & 7) * 8))];
}
__device__ __forceinline__ void wr2u(short* base, int row, int col2, u16 a, u16 b) {
    int idx = row * 64 + (((col2 & 56) ^ ((row & 7) << 3)) | (col2 & 6));
    *(u32*)&base[idx] = (u32)a | ((u32)b << 16);
}

// ---------------------------------------------------------------------------
// C[m,n] = A[m,:] . W[n,:]  (bf16, fp32 acc). Tile 128x128, BK=32, 4 waves.
// LDS octet-XOR swizzled (via pre-swizzled GLOBAL source; LDS dest linear).
// WITH_DT: spill raw cols [D_IN_PROJ-8, D_IN_PROJ) to fp32 dtout.
// ---------------------------------------------------------------------------
template <typename OUT, bool WITH_DT>
__global__ __launch_bounds__(256) void gemm_mfma(const short* __restrict__ A,
                                                 const short* __restrict__ W,
                                                 OUT* __restrict__ C,
                                                 float* __restrict__ dtout,
                                                 int N, int K, int lda) {
    __shared__ short As[128 * 32];
    __shared__ short Ws[128 * 32];
    const int tid  = threadIdx.x;
    const int m0   = blockIdx.y * 128;
    const int n0   = blockIdx.x * 128;
    const int wave = tid >> 6;
    const int lane = tid & 63;
    const int wm   = (wave & 1) * 64;
    const int wn   = (wave >> 1) * 64;
    const int lm   = lane & 15;
    const int lq   = lane >> 4;

    const int sr   = tid >> 2;
    const int soct = (tid & 3) ^ (sr & 3);       // swizzled source octet
    const short* ga = A + (size_t)(m0 + sr) * lda + soct * 8;
    const short* gw = W + (size_t)(n0 + sr) * K + soct * 8;
    short* la = &As[tid * 8];
    short* lw = &Ws[tid * 8];
    const size_t ga2 = (size_t)64 * lda;         // (sr+64)&3 == sr&3: same soct
    const size_t gw2 = (size_t)64 * K;

    const int oa = (lq ^ (lm & 3)) * 8;          // swizzled read octet offset

    f32x4 acc[4][4] = {};

    for (int k0 = 0; k0 < K; k0 += 32) {
        cp16(ga,       la);
        cp16(ga + ga2, la + 64 * 32);
        cp16(gw,       lw);
        cp16(gw + gw2, lw + 64 * 32);
        ga += 32; gw += 32;
        __syncthreads();
        bf16x8 af[4], bfr[4];
        #pragma unroll
        for (int i = 0; i < 4; i++) {
            af[i]  = *(const bf16x8*)&As[(wm + i * 16 + lm) * 32 + oa];
            bfr[i] = *(const bf16x8*)&Ws[(wn + i * 16 + lm) * 32 + oa];
        }
        #pragma unroll
        for (int i = 0; i < 4; i++)
            #pragma unroll
            for (int j = 0; j < 4; j++)
                acc[i][j] = __builtin_amdgcn_mfma_f32_16x16x32_bf16(af[i], bfr[j], acc[i][j], 0, 0, 0);
        __syncthreads();
    }
    #pragma unroll
    for (int i = 0; i < 4; i++)
        #pragma unroll
        for (int r = 0; r < 4; r++) {
            int m = m0 + wm + i * 16 + lq * 4 + r;
            #pragma unroll
            for (int j = 0; j < 4; j++) {
                int n = n0 + wn + j * 16 + lm;
                float v = acc[i][j][r];
                store_out(&C[(size_t)m * N + n], v);
                if (WITH_DT) {
                    if (n >= D_IN_PROJ - NHEADS && n < D_IN_PROJ)
                        dtout[(size_t)m * NHEADS + (n - (D_IN_PROJ - NHEADS))] = v;
                }
            }
        }
}

// ---------------------------------------------------------------------------
// Fused casts: x -> bf16, in_proj_w -> padded bf16, out_proj_w -> bf16.
// ---------------------------------------------------------------------------
#define NX_C  (NROWS * D_MODEL)
#define NWI_C (2 * ZXP * D_MODEL)
#define NWO_C (2 * D_MODEL * D_INNER)
__global__ __launch_bounds__(256) void cast_all_kernel(
    const float* __restrict__ x, const float* __restrict__ wi,
    const float* __restrict__ wo,
    u16* __restrict__ xb, u16* __restrict__ wib, u16* __restrict__ wob)
{
    int idx = blockIdx.x * 256 + threadIdx.x;
    if (idx < NX_C) { xb[idx] = bfc(x[idx]); return; }
    idx -= NX_C;
    if (idx < NWI_C) {
        int k = idx & 255;
        int rb = idx >> 8;
        int r = rb % ZXP;
        int blk = rb / ZXP;
        float v = (r < D_IN_PROJ)
            ? wi[(size_t)blk * D_IN_PROJ * D_MODEL + (size_t)r * D_MODEL + k] : 0.f;
        wib[idx] = bfc(v);
        return;
    }
    idx -= NWI_C;
    wob[idx] = bfc(wo[idx]);
}

// ---------------------------------------------------------------------------
// SSD intra-chunk, MFMA, with FULLY fused depthwise conv+SiLU (x slice + B +
// C) staged straight from zx with 3-row causal halo. One block per
// (b, chunk, head). h==0 block writes compact conv'd C rows to Cb.
// D*x folded into ys.
// ---------------------------------------------------------------------------
__global__ __launch_bounds__(256) void ssd_intra_kernel(
    const u16* __restrict__ zx,
    const float* __restrict__ dtbuf,
    const float* __restrict__ dt_bias, const float* __restrict__ A_log,
    const float* __restrict__ cw, const float* __restrict__ cb,
    const float* __restrict__ Dp,
    u16* __restrict__ ys, u16* __restrict__ Schunk,
    float* __restrict__ adec, u16* __restrict__ Cb)
{
    const int h   = blockIdx.x & 7;
    const int c   = (blockIdx.x >> 3) & 15;
    const int b   = blockIdx.x >> 7;
    const int tid = threadIdx.x;
    const int row0 = b * SEQLEN + c * CHUNK;

    __shared__ short Xt[64 * 64];    // [p][t]
    __shared__ short Bn[64 * 64];    // [t][n]
    __shared__ short Cn[64 * 64];    // [t][n]  -> reused as MT [t][tau]
    __shared__ short BTw[64 * 64];   // [n][t], w-folded
    __shared__ float cums[64], dts_s[64], ws_s[64];
    __shared__ float4 wls[192];      // conv weights: [g*64+k]; g=0 x, 1 B, 2 C
    __shared__ float  bls[192];

    if (tid < 64) {
        const float A = -__expf(A_log[h] * 1.44269504089f);
        float raw = dtbuf[(size_t)(row0 + tid) * NHEADS + h] + dt_bias[h];
        float dtv = (raw > 20.f) ? raw : log1pf(__expf(raw));
        float v = dtv * A;
        #pragma unroll
        for (int off = 1; off < 64; off <<= 1) {
            float o = __shfl_up(v, off, 64);
            if (tid >= off) v += o;
        }
        float tot = __shfl(v, 63, 64);
        cums[tid]  = v;
        dts_s[tid] = dtv;
        ws_s[tid]  = __expf(tot - v) * dtv;
        adec[(size_t)(b * NHEADS + h) * SEQLEN + c * CHUNK + tid] = __expf(v);
    } else {
        int wi = tid - 64;               // 0..191
        int g = wi >> 6, k = wi & 63;
        int ch = (g == 0) ? h * HEADDIM + k : (g == 1 ? 512 + k : 576 + k);
        wls[wi] = *(const float4*)&cw[ch * 4];
        bls[wi] = cb[ch];
    }
    __syncthreads();

    {   // fused conv+SiLU staging for x (head slice), B, C from zx
        const int t2 = (tid >> 3) * 2;       // 0..62
        const int c8 = (tid & 7) * 8;        // 0..56
        const int lb = c * CHUNK + t2;       // sequence-local row index
        const u16* zb = zx + (size_t)(row0 + t2) * ZXP + D_INNER;
        const float w0 = ws_s[t2], w1 = ws_s[t2 + 1];
        u16x8 zz;
        #pragma unroll
        for (int q = 0; q < 8; q++) zz[q] = 0;

        #pragma unroll
        for (int g = 0; g < 3; g++) {
            const int gc = (g == 0) ? h * HEADDIM + c8 : (g == 1 ? 512 + c8 : 576 + c8);
            const u16* p = zb + gc;
            u16x8 r0 = (lb >= 3) ? *(const u16x8*)(p - 3 * ZXP) : zz;
            u16x8 r1 = (lb >= 2) ? *(const u16x8*)(p - 2 * ZXP) : zz;
            u16x8 r2 = (lb >= 1) ? *(const u16x8*)(p - 1 * ZXP) : zz;
            u16x8 r3 = *(const u16x8*)p;
            u16x8 r4 = *(const u16x8*)(p + ZXP);
            u16x8 o0, o1;
            #pragma unroll
            for (int k = 0; k < 8; k++) {
                float4 w4  = wls[g * 64 + c8 + k];
                float bias = bls[g * 64 + c8 + k];
                float a0 = bias, a1 = bias;
                a0 = fmaf(bf2f(r0[k]), w4.x, a0);
                a0 = fmaf(bf2f(r1[k]), w4.y, a0);
                a0 = fmaf(bf2f(r2[k]), w4.z, a0);
                a0 = fmaf(bf2f(r3[k]), w4.w, a0);
                a1 = fmaf(bf2f(r1[k]), w4.x, a1);
                a1 = fmaf(bf2f(r2[k]), w4.y, a1);
                a1 = fmaf(bf2f(r3[k]), w4.z, a1);
                a1 = fmaf(bf2f(r4[k]), w4.w, a1);
                float s0 = silu_f(a0);
                float s1 = silu_f(a1);
                if (g == 0) {
                    wr2u(Xt, c8 + k, t2, bfc(s0), bfc(s1));
                } else if (g == 1) {
                    o0[k] = bfc(s0); o1[k] = bfc(s1);
                    wr2u(BTw, c8 + k, t2, bfc(s0 * w0), bfc(s1 * w1));
                } else {
                    o0[k] = bfc(s0); o1[k] = bfc(s1);
                }
            }
            if (g == 1) {
                *(u16x8*)&Bn[swz(t2,     c8)] = o0;
                *(u16x8*)&Bn[swz(t2 + 1, c8)] = o1;
            } else if (g == 2) {
                *(u16x8*)&Cn[swz(t2,     c8)] = o0;
                *(u16x8*)&Cn[swz(t2 + 1, c8)] = o1;
                if (h == 0) {
                    *(u16x8*)&Cb[(size_t)(row0 + t2)     * 64 + c8] = o0;
                    *(u16x8*)&Cb[(size_t)(row0 + t2 + 1) * 64 + c8] = o1;
                }
            }
        }
    }
    __syncthreads();

    const int lane = tid & 63, w = tid >> 6;
    const int lm = lane & 15, lq = lane >> 4;
    const int tau0 = 16 * w + lq * 4;

    bf16x8 aG0 = ldfrag(Bn, 16 * w + lm, lq);
    bf16x8 aG1 = ldfrag(Bn, 16 * w + lm, 4 + lq);
    f32x4 g[4] = {};
    #pragma unroll
    for (int j = 0; j < 4; j++) {
        g[j] = __builtin_amdgcn_mfma_f32_16x16x32_bf16(aG0, ldfrag(Cn, 16 * j + lm, lq),     g[j], 0, 0, 0);
        g[j] = __builtin_amdgcn_mfma_f32_16x16x32_bf16(aG1, ldfrag(Cn, 16 * j + lm, 4 + lq), g[j], 0, 0, 0);
    }
    float ctau[4], dtau[4];
    *(float4*)&ctau[0] = *(const float4*)&cums[tau0];
    *(float4*)&dtau[0] = *(const float4*)&dts_s[tau0];
    s16x4 mp[4];
    #pragma unroll
    for (int j = 0; j < 4; j++) {
        int t = 16 * j + lm;
        float ct = cums[t];
        #pragma unroll
        for (int r = 0; r < 4; r++) {
            int tau = tau0 + r;
            float m = (t >= tau) ? g[j][r] * __expf(ct - ctau[r]) * dtau[r] : 0.f;
            mp[j][r] = (short)bfc(m);
        }
    }
    __syncthreads();
    #pragma unroll
    for (int j = 0; j < 4; j++)
        *(s16x4*)&Cn[swz(16 * j + lm, tau0)] = mp[j];   // MT[t][tau]
    __syncthreads();

    bf16x8 aY0 = ldfrag(Cn,  16 * w + lm, lq);
    bf16x8 aY1 = ldfrag(Cn,  16 * w + lm, 4 + lq);
    bf16x8 aS0 = ldfrag(BTw, 16 * w + lm, lq);
    bf16x8 aS1 = ldfrag(BTw, 16 * w + lm, 4 + lq);
    f32x4 yv[4] = {}, sv[4] = {};
    #pragma unroll
    for (int j = 0; j < 4; j++) {
        bf16x8 xf0 = ldfrag(Xt, 16 * j + lm, lq);
        bf16x8 xf1 = ldfrag(Xt, 16 * j + lm, 4 + lq);
        yv[j] = __builtin_amdgcn_mfma_f32_16x16x32_bf16(aY0, xf0, yv[j], 0, 0, 0);
        yv[j] = __builtin_amdgcn_mfma_f32_16x16x32_bf16(aY1, xf1, yv[j], 0, 0, 0);
        sv[j] = __builtin_amdgcn_mfma_f32_16x16x32_bf16(aS0, xf0, sv[j], 0, 0, 0);
        sv[j] = __builtin_amdgcn_mfma_f32_16x16x32_bf16(aS1, xf1, sv[j], 0, 0, 0);
    }
    const float Dh = Dp[h];
    const int mrow = 16 * w + lq * 4;
    #pragma unroll
    for (int j = 0; j < 4; j++)
        #pragma unroll
        for (int r = 0; r < 4; r++) {
            float xv = bf2f((u16)Xt[swz(16 * j + lm, mrow + r)]);
            ys[(size_t)(row0 + mrow + r) * D_INNER + h * HEADDIM + 16 * j + lm]
                = bfc(yv[j][r] + Dh * xv);
        }
    u16* sb = Schunk + (size_t)((b * NCHUNK + c) * NHEADS + h) * 4096;
    #pragma unroll
    for (int j = 0; j < 4; j++)
        #pragma unroll
        for (int r = 0; r < 4; r++)
            sb[(mrow + r) * 64 + 16 * j + lm] = bfc(sv[j][r]);
}

// ---------------------------------------------------------------------------
// Parallel prefix scan over chunk states.
// ---------------------------------------------------------------------------
__global__ __launch_bounds__(256) void ssd_state_scan_kernel(
    u16* __restrict__ Schunk, const float* __restrict__ adec)
{
    const int q  = blockIdx.x & 3;
    const int bh = blockIdx.x >> 2;
    const int b  = bh >> 3, h = bh & 7;
    const int base = q * 1024 + threadIdx.x * 4;

    u16x4 v[NCHUNK];
    float atot[NCHUNK];
    #pragma unroll
    for (int c = 0; c < NCHUNK; c++) {
        v[c] = *(const u16x4*)&Schunk[(size_t)((b * NCHUNK + c) * NHEADS + h) * 4096 + base];
        atot[c] = adec[(size_t)bh * SEQLEN + c * CHUNK + 63];
    }
    float run[4] = {0.f, 0.f, 0.f, 0.f};
    #pragma unroll
    for (int c = 0; c < NCHUNK; c++) {
        u16x4 pv;
        #pragma unroll
        for (int k = 0; k < 4; k++) pv[k] = bfc(run[k]);
        *(u16x4*)&Schunk[(size_t)((b * NCHUNK + c) * NHEADS + h) * 4096 + base] = pv;
        #pragma unroll
        for (int k = 0; k < 4; k++)
            run[k] = fmaf(atot[c], run[k], bf2f(v[c][k]));
    }
}

// ---------------------------------------------------------------------------
// FUSED inter + gate + RMS + out_proj. One block per (b, chunk, 32-row half):
// 256 blocks x 512 threads (8 waves). Double-buffered STs (head loop) and
// Ws (wo-GEMM loop): one barrier per iteration, staging overlapped with
// compute. LDS ~100KB, 1 block/CU (grid == CU count).
// ---------------------------------------------------------------------------
template <typename OUT>
__global__ __launch_bounds__(512) void ssd_finish_proj_kernel(
    const u16* __restrict__ Cb, const u16* __restrict__ zx,
    const u16* __restrict__ ysin, const u16* __restrict__ Schunk,
    const float* __restrict__ adec, const float* __restrict__ nw,
    const u16* __restrict__ wo, OUT* __restrict__ Cout)
{
    const int half = blockIdx.x & 1;
    const int c    = (blockIdx.x >> 1) & 15;
    const int b    = blockIdx.x >> 5;
    const int tid  = threadIdx.x;
    const int row0 = b * SEQLEN + c * CHUNK + half * 32;

    // LDS layout (shorts): y_lds[16384] | region [16384,49152):
    //   head phase: Ct[2048] STs0[4096] STs1[4096]; gemm phase: Ws0/Ws1[16384 ea]
    // floats at short-offset 49152 (a_s 256, nw_s 512, ps 128, scl 32)
    __shared__ __align__(16) short smem[51008];
    short* y_lds = smem;
    short* Ct    = smem + 16384;
    short* STs0  = smem + 16384 + 2048;
    short* STs1  = STs0 + 4096;
    short* Ws0   = smem + 16384;
    short* Ws1   = smem + 32768;
    float* fb    = (float*)(smem + 49152);
    float* a_s   = fb;           // 256
    float* nw_s  = fb + 256;     // 512
    float* ps    = fb + 768;     // 128
    float* scl   = fb + 896;     // 32

    const int lane = tid & 63, w = tid >> 6;
    const int lm = lane & 15, lq = lane >> 4;
    const int rf  = w & 1;       // row-frag (16 rows each)
    const int cf4 = w >> 1;      // 0..3

    nw_s[tid] = nw[tid];
    if (tid < 256) {
        int t2 = tid >> 3, n8 = (tid & 7) * 8;   // Ct stage
        *(u16x8*)&Ct[swz(t2, n8)] = *(const u16x8*)&Cb[(size_t)(row0 + t2) * 64 + n8];
        a_s[tid] = adec[(size_t)(b * NHEADS + (tid >> 5)) * SEQLEN + c * CHUNK + half * 32 + (tid & 31)];
        // STs stage for h=0
        const u16* sb = Schunk + (size_t)((b * NCHUNK + c) * NHEADS) * 4096;
        int n2 = (tid >> 3) * 2, p8 = (tid & 7) * 8;
        u16x8 s0 = *(const u16x8*)&sb[(size_t)n2 * 64 + p8];
        u16x8 s1 = *(const u16x8*)&sb[(size_t)(n2 + 1) * 64 + p8];
        #pragma unroll
        for (int k = 0; k < 8; k++)
            wr2u(STs0, p8 + k, n2, s0[k], s1[k]);
    }
    __syncthreads();

    bf16x8 aC0 = ldfrag(Ct, 16 * rf + lm, lq);
    bf16x8 aC1 = ldfrag(Ct, 16 * rf + lm, 4 + lq);
    float ssloc[4] = {0.f, 0.f, 0.f, 0.f};

    for (int h = 0; h < 8; h++) {
        short* Scur = (h & 1) ? STs1 : STs0;
        short* Snxt = (h & 1) ? STs0 : STs1;
        if (h < 7 && tid < 256) {      // stage next head's S^T into alt buffer
            const u16* sb = Schunk + (size_t)((b * NCHUNK + c) * NHEADS + h + 1) * 4096;
            int n2 = (tid >> 3) * 2, p8 = (tid & 7) * 8;
            u16x8 s0 = *(const u16x8*)&sb[(size_t)n2 * 64 + p8];
            u16x8 s1 = *(const u16x8*)&sb[(size_t)(n2 + 1) * 64 + p8];
            #pragma unroll
            for (int k = 0; k < 8; k++)
                wr2u(Snxt, p8 + k, n2, s0[k], s1[k]);
        }
        const int n = cf4 * 16 + lm;
        f32x4 U = {};
        U = __builtin_amdgcn_mfma_f32_16x16x32_bf16(aC0, ldfrag(Scur, n, lq),     U, 0, 0, 0);
        U = __builtin_amdgcn_mfma_f32_16x16x32_bf16(aC1, ldfrag(Scur, n, 4 + lq), U, 0, 0, 0);
        {   // epilogue for head h (overlaps next-head staging)
            const int col = h * 64 + cf4 * 16 + lm;
            const float nwv = nw_s[col];
            #pragma unroll
            for (int r = 0; r < 4; r++) {
                int row = 16 * rf + lq * 4 + r;
                size_t grow = (size_t)(row0 + row);
                float u = U[r] * a_s[h * 32 + row] + bf2f(ysin[grow * D_INNER + col]);
                float zv = bf2f(zx[grow * ZXP + col]);
                float v = u * silu_f(zv);
                ssloc[r] = fmaf(v, v, ssloc[r]);
                y_lds[row * 512 + ((((col >> 3) ^ (row & 7)) << 3) | (col & 7))] = (short)bfc(v * nwv);
            }
        }
        __syncthreads();   // publish Snxt; guard Scur reuse at h+1
    }

    // prefetch wo slice 0 (overlaps RMS reduce); Ws region free after last barrier
    {
        int rr = tid >> 3, oc = tid & 7;
        #pragma unroll
        for (int q = 0; q < 4; q++) {
            int row = rr + q * 64;
            const u16* src = wo + (size_t)row * 512 + ((oc ^ (row & 7)) * 8);
            cp16((const short*)src, &Ws0[q * 4096 + tid * 8]);
        }
    }

    // row sum-of-squares -> scl
    #pragma unroll
    for (int r = 0; r < 4; r++) {
        float s = ssloc[r];
        s += __shfl_xor(s, 1, 64); s += __shfl_xor(s, 2, 64);
        s += __shfl_xor(s, 4, 64); s += __shfl_xor(s, 8, 64);
        if (lm == 0) ps[cf4 * 32 + 16 * rf + lq * 4 + r] = s;
    }
    __syncthreads();
    if (tid < 32)
        scl[tid] = rsqrtf((ps[tid] + ps[32 + tid] + ps[64 + tid] + ps[96 + tid])
                          * (1.f / (float)D_INNER) + EPS);
    __syncthreads();   // publish scl; Ws0 cp16s drained

    // out-proj: out[32x256] = y[32x512] @ wo^T, 8 K-slices of 64, dbuf Ws
    f32x4 acc[4] = {};
    const int arow = 16 * rf + lm;
    for (int kk = 0; kk < 8; kk++) {
        short* Wcur = (kk & 1) ? Ws1 : Ws0;
        short* Wnxt = (kk & 1) ? Ws0 : Ws1;
        if (kk < 7) {   // issue next slice's staging; flight covered by MFMAs
            int rr = tid >> 3, oc = tid & 7;
            #pragma unroll
            for (int q = 0; q < 4; q++) {
                int row = rr + q * 64;
                const u16* src = wo + (size_t)row * 512 + (kk + 1) * 64 + ((oc ^ (row & 7)) * 8);
                cp16((const short*)src, &Wnxt[q * 4096 + tid * 8]);
            }
        }
        bf16x8 aY0 = *(const bf16x8*)&y_lds[arow * 512 + ((kk * 8) | (lq       ^ (arow & 7))) * 8];
        bf16x8 aY1 = *(const bf16x8*)&y_lds[arow * 512 + ((kk * 8) | ((4 + lq) ^ (arow & 7))) * 8];
        #pragma unroll
        for (int j = 0; j < 4; j++) {
            int n = cf4 * 64 + j * 16 + lm;
            acc[j] = __builtin_amdgcn_mfma_f32_16x16x32_bf16(aY0, ldfrag(Wcur, n, lq),     acc[j], 0, 0, 0);
            acc[j] = __builtin_amdgcn_mfma_f32_16x16x32_bf16(aY1, ldfrag(Wcur, n, 4 + lq), acc[j], 0, 0, 0);
        }
        if (kk < 7) __syncthreads();   // drain next-slice cp16s; guard Wcur reuse
    }
    const int mrow = 16 * rf + lq * 4;
    #pragma unroll
    for (int r = 0; r < 4; r++) {
        float scale = scl[mrow + r];
        size_t m = (size_t)(row0 + mrow + r);
        #pragma unroll
        for (int j = 0; j < 4; j++) {
            int n = cf4 * 64 + j * 16 + lm;
            store_out(&Cout[m * D_MODEL + n], acc[j][r] * scale);
        }
    }
}

// ---------------------------------------------------------------------------
extern "C" void kernel_launch(void* const* d_in, const int* in_sizes, int n_in,
                              void* d_out, int out_size, void* d_ws, size_t ws_size,
                              hipStream_t stream) {
    const float* x          = (const float*)d_in[0];
    const float* in_proj_w  = (const float*)d_in[1];
    const float* conv_w     = (const float*)d_in[2];
    const float* conv_b     = (const float*)d_in[3];
    const float* dt_bias    = (const float*)d_in[4];
    const float* A_log      = (const float*)d_in[5];
    const float* Dp         = (const float*)d_in[6];
    const float* norm_w     = (const float*)d_in[7];
    const float* out_proj_w = (const float*)d_in[8];
    float* out = (float*)d_out;

    u16*   buf_zx = (u16*)d_ws;                                      // 8192 x 1280 bf16
    u16*   buf_cb = buf_zx + (size_t)NROWS * ZXP;                    // 8192 x 64   bf16 (conv'd C)
    u16*   buf_ys = buf_cb + (size_t)NROWS * 64;                     // 8192 x 512  bf16
    u16*   buf_S  = buf_ys + (size_t)NROWS * D_INNER;                // 128*8*4096  bf16
    u16*   buf_hb = buf_S  + (size_t)BATCH * NCHUNK * NHEADS * 4096; // 8192 x 256  bf16
    u16*   buf_wi = buf_hb + (size_t)NROWS * D_MODEL;                // 2x1280x256  bf16
    u16*   buf_wo = buf_wi + (size_t)2 * ZXP * D_MODEL;              // 2x256x512   bf16
    float* buf_dt = (float*)(buf_wo + (size_t)2 * D_MODEL * D_INNER);// 8192 x 8    f32
    float* buf_a  = buf_dt + (size_t)NROWS * NHEADS;                 // 64 x 1024   f32

    cast_all_kernel<<<(NX_C + NWI_C + NWO_C) / 256, 256, 0, stream>>>(
        x, in_proj_w, out_proj_w, buf_hb, buf_wi, buf_wo);

    for (int i = 0; i < 2; i++) {
        gemm_mfma<__hip_bfloat16, true><<<dim3(ZXP / 128, NROWS / 128), 256, 0, stream>>>(
            (const short*)buf_hb, (const short*)(buf_wi + (size_t)i * ZXP * D_MODEL),
            (__hip_bfloat16*)buf_zx, buf_dt, ZXP, D_MODEL, D_MODEL);

        ssd_intra_kernel<<<BATCH * NCHUNK * NHEADS, 256, 0, stream>>>(
            buf_zx, buf_dt,
            dt_bias + i * NHEADS, A_log + i * NHEADS,
            conv_w + (size_t)i * CONV_DIM * D_CONV, conv_b + (size_t)i * CONV_DIM,
            Dp + i * NHEADS, buf_ys, buf_S, buf_a, buf_cb);

        ssd_state_scan_kernel<<<BATCH * NHEADS * 4, 256, 0, stream>>>(buf_S, buf_a);

        if (i == 0) {
            ssd_finish_proj_kernel<__hip_bfloat16><<<BATCH * NCHUNK * 2, 512, 0, stream>>>(
                buf_cb, buf_zx, buf_ys, buf_S, buf_a,
                norm_w, (const u16*)buf_wo, (__hip_bfloat16*)buf_hb);
        } else {
            ssd_finish_proj_kernel<float><<<BATCH * NCHUNK * 2, 512, 0, stream>>>(
                buf_cb, buf_zx, buf_ys, buf_S, buf_a,
                norm_w + D_INNER, (const u16*)(buf_wo + (size_t)D_MODEL * D_INNER), out);
        }
    }
}

// Round 11
// 172.146 us; speedup vs baseline: 4.0458x; 1.0117x over previous
//
#include <hip/hip_runtime.h>
#include <hip/hip_bf16.h>
#include <math.h>

#define D_MODEL   256
#define D_STATE   64
#define D_CONV    4
#define D_INNER   512
#define HEADDIM   64
#define NHEADS    8
#define CONV_DIM  640     // D_INNER + 2*D_STATE
#define D_IN_PROJ 1160    // 2*D_INNER + 2*D_STATE + NHEADS
#define ZXP       1280    // padded in_proj N (10 x 128 tiles)
#define SEQLEN    1024
#define BATCH     8
#define NROWS     8192    // BATCH * SEQLEN
#define EPS       1e-5f
#define CHUNK     64
#define NCHUNK    (SEQLEN / CHUNK)   // 16

typedef __attribute__((ext_vector_type(8))) short bf16x8;
typedef __attribute__((ext_vector_type(4))) short s16x4;
typedef __attribute__((ext_vector_type(8))) unsigned short u16x8;
typedef __attribute__((ext_vector_type(4))) unsigned short u16x4;
typedef __attribute__((ext_vector_type(4))) float f32x4;
typedef unsigned int u32;
typedef unsigned short u16;

__device__ __forceinline__ void cp16(const short* g, short* l) {
    __builtin_amdgcn_global_load_lds((const __attribute__((address_space(1))) u32*)g,
                                     (__attribute__((address_space(3))) u32*)l, 16, 0, 0);
}
__device__ __forceinline__ u16 bfc(float f) {
    union { __hip_bfloat16 h; u16 u; } cv;
    cv.h = __float2bfloat16(f);
    return cv.u;
}
__device__ __forceinline__ float bf2f(u16 u) {
    union { u32 v; float f; } cv;
    cv.v = ((u32)u) << 16;
    return cv.f;
}
__device__ __forceinline__ float silu_f(float a) {
    return a * __builtin_amdgcn_rcpf(1.f + __expf(-a));
}
__device__ __forceinline__ void store_out(float* p, float v) { *p = v; }
__device__ __forceinline__ void store_out(__hip_bfloat16* p, float v) { *p = __float2bfloat16(v); }

// 64-col bf16 LDS tile, XOR-octet swizzle
__device__ __forceinline__ int swz(int row, int col) {
    return row * 64 + (((col & 56) ^ ((row & 7) << 3)) | (col & 7));
}
__device__ __forceinline__ bf16x8 ldfrag(const short* base, int row, int oct) {
    return *(const bf16x8*)&base[row * 64 + ((oct * 8) ^ ((row & 7) * 8))];
}
__device__ __forceinline__ void wr2u(short* base, int row, int col2, u16 a, u16 b) {
    int idx = row * 64 + (((col2 & 56) ^ ((row & 7) << 3)) | (col2 & 6));
    *(u32*)&base[idx] = (u32)a | ((u32)b << 16);
}

// ---------------------------------------------------------------------------
// C[m,n] = A[m,:] . W[n,:]  (bf16, fp32 acc). Tile 128x128, BK=32, 4 waves.
// 2-PHASE pipeline (T3-minimum): stage next K-step BEFORE current MFMAs,
// one barrier per K-step (cp16 flight covered by MFMAs). LDS dbuf 32KB.
// LDS octet-XOR swizzled (via pre-swizzled GLOBAL source; LDS dest linear).
// WITH_DT: spill raw cols [D_IN_PROJ-8, D_IN_PROJ) to fp32 dtout.
// ---------------------------------------------------------------------------
template <typename OUT, bool WITH_DT>
__global__ __launch_bounds__(256) void gemm_mfma(const short* __restrict__ A,
                                                 const short* __restrict__ W,
                                                 OUT* __restrict__ C,
                                                 float* __restrict__ dtout,
                                                 int N, int K, int lda) {
    __shared__ short As[2 * 4096];   // [buf][128 rows x 32 k]
    __shared__ short Wsm[2 * 4096];
    const int tid  = threadIdx.x;
    const int m0   = blockIdx.y * 128;
    const int n0   = blockIdx.x * 128;
    const int wave = tid >> 6;
    const int lane = tid & 63;
    const int wm   = (wave & 1) * 64;
    const int wn   = (wave >> 1) * 64;
    const int lm   = lane & 15;
    const int lq   = lane >> 4;

    const int sr   = tid >> 2;
    const int soct = (tid & 3) ^ (sr & 3);       // swizzled source octet
    const short* ga = A + (size_t)(m0 + sr) * lda + soct * 8;
    const short* gw = W + (size_t)(n0 + sr) * K + soct * 8;
    const size_t ga2 = (size_t)64 * lda;         // (sr+64)&3 == sr&3: same soct
    const size_t gw2 = (size_t)64 * K;

    const int oa = (lq ^ (lm & 3)) * 8;          // swizzled read octet offset
    const int nt = K >> 5;                       // K-steps of 32

    // prologue: stage step 0 into buf 0
    cp16(ga,       &As[tid * 8]);
    cp16(ga + ga2, &As[2048 + tid * 8]);
    cp16(gw,       &Wsm[tid * 8]);
    cp16(gw + gw2, &Wsm[2048 + tid * 8]);
    __syncthreads();

    f32x4 acc[4][4] = {};

    for (int t = 0; t < nt; ++t) {
        const int cur = (t & 1) * 4096;
        if (t + 1 < nt) {            // issue next step's loads into alt buffer
            const int alt = ((t + 1) & 1) * 4096;
            const short* gaN = ga + (size_t)(t + 1) * 32;
            const short* gwN = gw + (size_t)(t + 1) * 32;
            cp16(gaN,       &As[alt + tid * 8]);
            cp16(gaN + ga2, &As[alt + 2048 + tid * 8]);
            cp16(gwN,       &Wsm[alt + tid * 8]);
            cp16(gwN + gw2, &Wsm[alt + 2048 + tid * 8]);
        }
        bf16x8 af[4], bfr[4];
        #pragma unroll
        for (int i = 0; i < 4; i++) {
            af[i]  = *(const bf16x8*)&As[cur + (wm + i * 16 + lm) * 32 + oa];
            bfr[i] = *(const bf16x8*)&Wsm[cur + (wn + i * 16 + lm) * 32 + oa];
        }
        #pragma unroll
        for (int i = 0; i < 4; i++)
            #pragma unroll
            for (int j = 0; j < 4; j++)
                acc[i][j] = __builtin_amdgcn_mfma_f32_16x16x32_bf16(af[i], bfr[j], acc[i][j], 0, 0, 0);
        if (t + 1 < nt) __syncthreads();   // drain next-step cp16s; guard buffer swap
    }
    #pragma unroll
    for (int i = 0; i < 4; i++)
        #pragma unroll
        for (int r = 0; r < 4; r++) {
            int m = m0 + wm + i * 16 + lq * 4 + r;
            #pragma unroll
            for (int j = 0; j < 4; j++) {
                int n = n0 + wn + j * 16 + lm;
                float v = acc[i][j][r];
                store_out(&C[(size_t)m * N + n], v);
                if (WITH_DT) {
                    if (n >= D_IN_PROJ - NHEADS && n < D_IN_PROJ)
                        dtout[(size_t)m * NHEADS + (n - (D_IN_PROJ - NHEADS))] = v;
                }
            }
        }
}

// ---------------------------------------------------------------------------
// Fused casts: x -> bf16, in_proj_w -> padded bf16, out_proj_w -> bf16.
// ---------------------------------------------------------------------------
#define NX_C  (NROWS * D_MODEL)
#define NWI_C (2 * ZXP * D_MODEL)
#define NWO_C (2 * D_MODEL * D_INNER)
__global__ __launch_bounds__(256) void cast_all_kernel(
    const float* __restrict__ x, const float* __restrict__ wi,
    const float* __restrict__ wo,
    u16* __restrict__ xb, u16* __restrict__ wib, u16* __restrict__ wob)
{
    int idx = blockIdx.x * 256 + threadIdx.x;
    if (idx < NX_C) { xb[idx] = bfc(x[idx]); return; }
    idx -= NX_C;
    if (idx < NWI_C) {
        int k = idx & 255;
        int rb = idx >> 8;
        int r = rb % ZXP;
        int blk = rb / ZXP;
        float v = (r < D_IN_PROJ)
            ? wi[(size_t)blk * D_IN_PROJ * D_MODEL + (size_t)r * D_MODEL + k] : 0.f;
        wib[idx] = bfc(v);
        return;
    }
    idx -= NWI_C;
    wob[idx] = bfc(wo[idx]);
}

// ---------------------------------------------------------------------------
// SSD intra-chunk, MFMA, with FULLY fused depthwise conv+SiLU (x slice + B +
// C) staged straight from zx with 3-row causal halo. One block per
// (b, chunk, head). h==0 block writes compact conv'd C rows to Cb.
// D*x folded into ys.
// ---------------------------------------------------------------------------
__global__ __launch_bounds__(256) void ssd_intra_kernel(
    const u16* __restrict__ zx,
    const float* __restrict__ dtbuf,
    const float* __restrict__ dt_bias, const float* __restrict__ A_log,
    const float* __restrict__ cw, const float* __restrict__ cb,
    const float* __restrict__ Dp,
    u16* __restrict__ ys, u16* __restrict__ Schunk,
    float* __restrict__ adec, u16* __restrict__ Cb)
{
    const int h   = blockIdx.x & 7;
    const int c   = (blockIdx.x >> 3) & 15;
    const int b   = blockIdx.x >> 7;
    const int tid = threadIdx.x;
    const int row0 = b * SEQLEN + c * CHUNK;

    __shared__ short Xt[64 * 64];    // [p][t]
    __shared__ short Bn[64 * 64];    // [t][n]
    __shared__ short Cn[64 * 64];    // [t][n]  -> reused as MT [t][tau]
    __shared__ short BTw[64 * 64];   // [n][t], w-folded
    __shared__ float cums[64], dts_s[64], ws_s[64];
    __shared__ float4 wls[192];      // conv weights: [g*64+k]; g=0 x, 1 B, 2 C
    __shared__ float  bls[192];

    if (tid < 64) {
        const float A = -__expf(A_log[h] * 1.44269504089f);
        float raw = dtbuf[(size_t)(row0 + tid) * NHEADS + h] + dt_bias[h];
        float dtv = (raw > 20.f) ? raw : log1pf(__expf(raw));
        float v = dtv * A;
        #pragma unroll
        for (int off = 1; off < 64; off <<= 1) {
            float o = __shfl_up(v, off, 64);
            if (tid >= off) v += o;
        }
        float tot = __shfl(v, 63, 64);
        cums[tid]  = v;
        dts_s[tid] = dtv;
        ws_s[tid]  = __expf(tot - v) * dtv;
        adec[(size_t)(b * NHEADS + h) * SEQLEN + c * CHUNK + tid] = __expf(v);
    } else {
        int wi = tid - 64;               // 0..191
        int g = wi >> 6, k = wi & 63;
        int ch = (g == 0) ? h * HEADDIM + k : (g == 1 ? 512 + k : 576 + k);
        wls[wi] = *(const float4*)&cw[ch * 4];
        bls[wi] = cb[ch];
    }
    __syncthreads();

    {   // fused conv+SiLU staging for x (head slice), B, C from zx
        const int t2 = (tid >> 3) * 2;       // 0..62
        const int c8 = (tid & 7) * 8;        // 0..56
        const int lb = c * CHUNK + t2;       // sequence-local row index
        const u16* zb = zx + (size_t)(row0 + t2) * ZXP + D_INNER;
        const float w0 = ws_s[t2], w1 = ws_s[t2 + 1];
        u16x8 zz;
        #pragma unroll
        for (int q = 0; q < 8; q++) zz[q] = 0;

        #pragma unroll
        for (int g = 0; g < 3; g++) {
            const int gc = (g == 0) ? h * HEADDIM + c8 : (g == 1 ? 512 + c8 : 576 + c8);
            const u16* p = zb + gc;
            u16x8 r0 = (lb >= 3) ? *(const u16x8*)(p - 3 * ZXP) : zz;
            u16x8 r1 = (lb >= 2) ? *(const u16x8*)(p - 2 * ZXP) : zz;
            u16x8 r2 = (lb >= 1) ? *(const u16x8*)(p - 1 * ZXP) : zz;
            u16x8 r3 = *(const u16x8*)p;
            u16x8 r4 = *(const u16x8*)(p + ZXP);
            u16x8 o0, o1;
            #pragma unroll
            for (int k = 0; k < 8; k++) {
                float4 w4  = wls[g * 64 + c8 + k];
                float bias = bls[g * 64 + c8 + k];
                float a0 = bias, a1 = bias;
                a0 = fmaf(bf2f(r0[k]), w4.x, a0);
                a0 = fmaf(bf2f(r1[k]), w4.y, a0);
                a0 = fmaf(bf2f(r2[k]), w4.z, a0);
                a0 = fmaf(bf2f(r3[k]), w4.w, a0);
                a1 = fmaf(bf2f(r1[k]), w4.x, a1);
                a1 = fmaf(bf2f(r2[k]), w4.y, a1);
                a1 = fmaf(bf2f(r3[k]), w4.z, a1);
                a1 = fmaf(bf2f(r4[k]), w4.w, a1);
                float s0 = silu_f(a0);
                float s1 = silu_f(a1);
                if (g == 0) {
                    wr2u(Xt, c8 + k, t2, bfc(s0), bfc(s1));
                } else if (g == 1) {
                    o0[k] = bfc(s0); o1[k] = bfc(s1);
                    wr2u(BTw, c8 + k, t2, bfc(s0 * w0), bfc(s1 * w1));
                } else {
                    o0[k] = bfc(s0); o1[k] = bfc(s1);
                }
            }
            if (g == 1) {
                *(u16x8*)&Bn[swz(t2,     c8)] = o0;
                *(u16x8*)&Bn[swz(t2 + 1, c8)] = o1;
            } else if (g == 2) {
                *(u16x8*)&Cn[swz(t2,     c8)] = o0;
                *(u16x8*)&Cn[swz(t2 + 1, c8)] = o1;
                if (h == 0) {
                    *(u16x8*)&Cb[(size_t)(row0 + t2)     * 64 + c8] = o0;
                    *(u16x8*)&Cb[(size_t)(row0 + t2 + 1) * 64 + c8] = o1;
                }
            }
        }
    }
    __syncthreads();

    const int lane = tid & 63, w = tid >> 6;
    const int lm = lane & 15, lq = lane >> 4;
    const int tau0 = 16 * w + lq * 4;

    bf16x8 aG0 = ldfrag(Bn, 16 * w + lm, lq);
    bf16x8 aG1 = ldfrag(Bn, 16 * w + lm, 4 + lq);
    f32x4 g[4] = {};
    #pragma unroll
    for (int j = 0; j < 4; j++) {
        g[j] = __builtin_amdgcn_mfma_f32_16x16x32_bf16(aG0, ldfrag(Cn, 16 * j + lm, lq),     g[j], 0, 0, 0);
        g[j] = __builtin_amdgcn_mfma_f32_16x16x32_bf16(aG1, ldfrag(Cn, 16 * j + lm, 4 + lq), g[j], 0, 0, 0);
    }
    float ctau[4], dtau[4];
    *(float4*)&ctau[0] = *(const float4*)&cums[tau0];
    *(float4*)&dtau[0] = *(const float4*)&dts_s[tau0];
    s16x4 mp[4];
    #pragma unroll
    for (int j = 0; j < 4; j++) {
        int t = 16 * j + lm;
        float ct = cums[t];
        #pragma unroll
        for (int r = 0; r < 4; r++) {
            int tau = tau0 + r;
            float m = (t >= tau) ? g[j][r] * __expf(ct - ctau[r]) * dtau[r] : 0.f;
            mp[j][r] = (short)bfc(m);
        }
    }
    __syncthreads();
    #pragma unroll
    for (int j = 0; j < 4; j++)
        *(s16x4*)&Cn[swz(16 * j + lm, tau0)] = mp[j];   // MT[t][tau]
    __syncthreads();

    bf16x8 aY0 = ldfrag(Cn,  16 * w + lm, lq);
    bf16x8 aY1 = ldfrag(Cn,  16 * w + lm, 4 + lq);
    bf16x8 aS0 = ldfrag(BTw, 16 * w + lm, lq);
    bf16x8 aS1 = ldfrag(BTw, 16 * w + lm, 4 + lq);
    f32x4 yv[4] = {}, sv[4] = {};
    #pragma unroll
    for (int j = 0; j < 4; j++) {
        bf16x8 xf0 = ldfrag(Xt, 16 * j + lm, lq);
        bf16x8 xf1 = ldfrag(Xt, 16 * j + lm, 4 + lq);
        yv[j] = __builtin_amdgcn_mfma_f32_16x16x32_bf16(aY0, xf0, yv[j], 0, 0, 0);
        yv[j] = __builtin_amdgcn_mfma_f32_16x16x32_bf16(aY1, xf1, yv[j], 0, 0, 0);
        sv[j] = __builtin_amdgcn_mfma_f32_16x16x32_bf16(aS0, xf0, sv[j], 0, 0, 0);
        sv[j] = __builtin_amdgcn_mfma_f32_16x16x32_bf16(aS1, xf1, sv[j], 0, 0, 0);
    }
    const float Dh = Dp[h];
    const int mrow = 16 * w + lq * 4;
    #pragma unroll
    for (int j = 0; j < 4; j++)
        #pragma unroll
        for (int r = 0; r < 4; r++) {
            float xv = bf2f((u16)Xt[swz(16 * j + lm, mrow + r)]);
            ys[(size_t)(row0 + mrow + r) * D_INNER + h * HEADDIM + 16 * j + lm]
                = bfc(yv[j][r] + Dh * xv);
        }
    u16* sb = Schunk + (size_t)((b * NCHUNK + c) * NHEADS + h) * 4096;
    #pragma unroll
    for (int j = 0; j < 4; j++)
        #pragma unroll
        for (int r = 0; r < 4; r++)
            sb[(mrow + r) * 64 + 16 * j + lm] = bfc(sv[j][r]);
}

// ---------------------------------------------------------------------------
// Parallel prefix scan over chunk states.
// ---------------------------------------------------------------------------
__global__ __launch_bounds__(256) void ssd_state_scan_kernel(
    u16* __restrict__ Schunk, const float* __restrict__ adec)
{
    const int q  = blockIdx.x & 3;
    const int bh = blockIdx.x >> 2;
    const int b  = bh >> 3, h = bh & 7;
    const int base = q * 1024 + threadIdx.x * 4;

    u16x4 v[NCHUNK];
    float atot[NCHUNK];
    #pragma unroll
    for (int c = 0; c < NCHUNK; c++) {
        v[c] = *(const u16x4*)&Schunk[(size_t)((b * NCHUNK + c) * NHEADS + h) * 4096 + base];
        atot[c] = adec[(size_t)bh * SEQLEN + c * CHUNK + 63];
    }
    float run[4] = {0.f, 0.f, 0.f, 0.f};
    #pragma unroll
    for (int c = 0; c < NCHUNK; c++) {
        u16x4 pv;
        #pragma unroll
        for (int k = 0; k < 4; k++) pv[k] = bfc(run[k]);
        *(u16x4*)&Schunk[(size_t)((b * NCHUNK + c) * NHEADS + h) * 4096 + base] = pv;
        #pragma unroll
        for (int k = 0; k < 4; k++)
            run[k] = fmaf(atot[c], run[k], bf2f(v[c][k]));
    }
}

// ---------------------------------------------------------------------------
// FUSED inter + gate + RMS + out_proj. One block per (b, chunk, 32-row half):
// 256 blocks x 512 threads (8 waves). Double-buffered STs (head loop) and
// Ws (wo-GEMM loop): one barrier per iteration, staging overlapped with
// compute. LDS ~100KB, 1 block/CU (grid == CU count).
// ---------------------------------------------------------------------------
template <typename OUT>
__global__ __launch_bounds__(512) void ssd_finish_proj_kernel(
    const u16* __restrict__ Cb, const u16* __restrict__ zx,
    const u16* __restrict__ ysin, const u16* __restrict__ Schunk,
    const float* __restrict__ adec, const float* __restrict__ nw,
    const u16* __restrict__ wo, OUT* __restrict__ Cout)
{
    const int half = blockIdx.x & 1;
    const int c    = (blockIdx.x >> 1) & 15;
    const int b    = blockIdx.x >> 5;
    const int tid  = threadIdx.x;
    const int row0 = b * SEQLEN + c * CHUNK + half * 32;

    // LDS layout (shorts): y_lds[16384] | region [16384,49152):
    //   head phase: Ct[2048] STs0[4096] STs1[4096]; gemm phase: Ws0/Ws1[16384 ea]
    // floats at short-offset 49152 (a_s 256, nw_s 512, ps 128, scl 32)
    __shared__ __align__(16) short smem[51008];
    short* y_lds = smem;
    short* Ct    = smem + 16384;
    short* STs0  = smem + 16384 + 2048;
    short* STs1  = STs0 + 4096;
    short* Ws0   = smem + 16384;
    short* Ws1   = smem + 32768;
    float* fb    = (float*)(smem + 49152);
    float* a_s   = fb;           // 256
    float* nw_s  = fb + 256;     // 512
    float* ps    = fb + 768;     // 128
    float* scl   = fb + 896;     // 32

    const int lane = tid & 63, w = tid >> 6;
    const int lm = lane & 15, lq = lane >> 4;
    const int rf  = w & 1;       // row-frag (16 rows each)
    const int cf4 = w >> 1;      // 0..3

    nw_s[tid] = nw[tid];
    if (tid < 256) {
        int t2 = tid >> 3, n8 = (tid & 7) * 8;   // Ct stage
        *(u16x8*)&Ct[swz(t2, n8)] = *(const u16x8*)&Cb[(size_t)(row0 + t2) * 64 + n8];
        a_s[tid] = adec[(size_t)(b * NHEADS + (tid >> 5)) * SEQLEN + c * CHUNK + half * 32 + (tid & 31)];
        // STs stage for h=0
        const u16* sb = Schunk + (size_t)((b * NCHUNK + c) * NHEADS) * 4096;
        int n2 = (tid >> 3) * 2, p8 = (tid & 7) * 8;
        u16x8 s0 = *(const u16x8*)&sb[(size_t)n2 * 64 + p8];
        u16x8 s1 = *(const u16x8*)&sb[(size_t)(n2 + 1) * 64 + p8];
        #pragma unroll
        for (int k = 0; k < 8; k++)
            wr2u(STs0, p8 + k, n2, s0[k], s1[k]);
    }
    __syncthreads();

    bf16x8 aC0 = ldfrag(Ct, 16 * rf + lm, lq);
    bf16x8 aC1 = ldfrag(Ct, 16 * rf + lm, 4 + lq);
    float ssloc[4] = {0.f, 0.f, 0.f, 0.f};

    for (int h = 0; h < 8; h++) {
        short* Scur = (h & 1) ? STs1 : STs0;
        short* Snxt = (h & 1) ? STs0 : STs1;
        if (h < 7 && tid < 256) {      // stage next head's S^T into alt buffer
            const u16* sb = Schunk + (size_t)((b * NCHUNK + c) * NHEADS + h + 1) * 4096;
            int n2 = (tid >> 3) * 2, p8 = (tid & 7) * 8;
            u16x8 s0 = *(const u16x8*)&sb[(size_t)n2 * 64 + p8];
            u16x8 s1 = *(const u16x8*)&sb[(size_t)(n2 + 1) * 64 + p8];
            #pragma unroll
            for (int k = 0; k < 8; k++)
                wr2u(Snxt, p8 + k, n2, s0[k], s1[k]);
        }
        const int n = cf4 * 16 + lm;
        f32x4 U = {};
        U = __builtin_amdgcn_mfma_f32_16x16x32_bf16(aC0, ldfrag(Scur, n, lq),     U, 0, 0, 0);
        U = __builtin_amdgcn_mfma_f32_16x16x32_bf16(aC1, ldfrag(Scur, n, 4 + lq), U, 0, 0, 0);
        {   // epilogue for head h (overlaps next-head staging)
            const int col = h * 64 + cf4 * 16 + lm;
            const float nwv = nw_s[col];
            #pragma unroll
            for (int r = 0; r < 4; r++) {
                int row = 16 * rf + lq * 4 + r;
                size_t grow = (size_t)(row0 + row);
                float u = U[r] * a_s[h * 32 + row] + bf2f(ysin[grow * D_INNER + col]);
                float zv = bf2f(zx[grow * ZXP + col]);
                float v = u * silu_f(zv);
                ssloc[r] = fmaf(v, v, ssloc[r]);
                y_lds[row * 512 + ((((col >> 3) ^ (row & 7)) << 3) | (col & 7))] = (short)bfc(v * nwv);
            }
        }
        __syncthreads();   // publish Snxt; guard Scur reuse at h+1
    }

    // prefetch wo slice 0 (overlaps RMS reduce); Ws region free after last barrier
    {
        int rr = tid >> 3, oc = tid & 7;
        #pragma unroll
        for (int q = 0; q < 4; q++) {
            int row = rr + q * 64;
            const u16* src = wo + (size_t)row * 512 + ((oc ^ (row & 7)) * 8);
            cp16((const short*)src, &Ws0[q * 4096 + tid * 8]);
        }
    }

    // row sum-of-squares -> scl
    #pragma unroll
    for (int r = 0; r < 4; r++) {
        float s = ssloc[r];
        s += __shfl_xor(s, 1, 64); s += __shfl_xor(s, 2, 64);
        s += __shfl_xor(s, 4, 64); s += __shfl_xor(s, 8, 64);
        if (lm == 0) ps[cf4 * 32 + 16 * rf + lq * 4 + r] = s;
    }
    __syncthreads();
    if (tid < 32)
        scl[tid] = rsqrtf((ps[tid] + ps[32 + tid] + ps[64 + tid] + ps[96 + tid])
                          * (1.f / (float)D_INNER) + EPS);
    __syncthreads();   // publish scl; Ws0 cp16s drained

    // out-proj: out[32x256] = y[32x512] @ wo^T, 8 K-slices of 64, dbuf Ws
    f32x4 acc[4] = {};
    const int arow = 16 * rf + lm;
    for (int kk = 0; kk < 8; kk++) {
        short* Wcur = (kk & 1) ? Ws1 : Ws0;
        short* Wnxt = (kk & 1) ? Ws0 : Ws1;
        if (kk < 7) {   // issue next slice's staging; flight covered by MFMAs
            int rr = tid >> 3, oc = tid & 7;
            #pragma unroll
            for (int q = 0; q < 4; q++) {
                int row = rr + q * 64;
                const u16* src = wo + (size_t)row * 512 + (kk + 1) * 64 + ((oc ^ (row & 7)) * 8);
                cp16((const short*)src, &Wnxt[q * 4096 + tid * 8]);
            }
        }
        bf16x8 aY0 = *(const bf16x8*)&y_lds[arow * 512 + ((kk * 8) | (lq       ^ (arow & 7))) * 8];
        bf16x8 aY1 = *(const bf16x8*)&y_lds[arow * 512 + ((kk * 8) | ((4 + lq) ^ (arow & 7))) * 8];
        #pragma unroll
        for (int j = 0; j < 4; j++) {
            int n = cf4 * 64 + j * 16 + lm;
            acc[j] = __builtin_amdgcn_mfma_f32_16x16x32_bf16(aY0, ldfrag(Wcur, n, lq),     acc[j], 0, 0, 0);
            acc[j] = __builtin_amdgcn_mfma_f32_16x16x32_bf16(aY1, ldfrag(Wcur, n, 4 + lq), acc[j], 0, 0, 0);
        }
        if (kk < 7) __syncthreads();   // drain next-slice cp16s; guard Wcur reuse
    }
    const int mrow = 16 * rf + lq * 4;
    #pragma unroll
    for (int r = 0; r < 4; r++) {
        float scale = scl[mrow + r];
        size_t m = (size_t)(row0 + mrow + r);
        #pragma unroll
        for (int j = 0; j < 4; j++) {
            int n = cf4 * 64 + j * 16 + lm;
            store_out(&Cout[m * D_MODEL + n], acc[j][r] * scale);
        }
    }
}

// ---------------------------------------------------------------------------
extern "C" void kernel_launch(void* const* d_in, const int* in_sizes, int n_in,
                              void* d_out, int out_size, void* d_ws, size_t ws_size,
                              hipStream_t stream) {
    const float* x          = (const float*)d_in[0];
    const float* in_proj_w  = (const float*)d_in[1];
    const float* conv_w     = (const float*)d_in[2];
    const float* conv_b     = (const float*)d_in[3];
    const float* dt_bias    = (const float*)d_in[4];
    const float* A_log      = (const float*)d_in[5];
    const float* Dp         = (const float*)d_in[6];
    const float* norm_w     = (const float*)d_in[7];
    const float* out_proj_w = (const float*)d_in[8];
    float* out = (float*)d_out;

    u16*   buf_zx = (u16*)d_ws;                                      // 8192 x 1280 bf16
    u16*   buf_cb = buf_zx + (size_t)NROWS * ZXP;                    // 8192 x 64   bf16 (conv'd C)
    u16*   buf_ys = buf_cb + (size_t)NROWS * 64;                     // 8192 x 512  bf16
    u16*   buf_S  = buf_ys + (size_t)NROWS * D_INNER;                // 128*8*4096  bf16
    u16*   buf_hb = buf_S  + (size_t)BATCH * NCHUNK * NHEADS * 4096; // 8192 x 256  bf16
    u16*   buf_wi = buf_hb + (size_t)NROWS * D_MODEL;                // 2x1280x256  bf16
    u16*   buf_wo = buf_wi + (size_t)2 * ZXP * D_MODEL;              // 2x256x512   bf16
    float* buf_dt = (float*)(buf_wo + (size_t)2 * D_MODEL * D_INNER);// 8192 x 8    f32
    float* buf_a  = buf_dt + (size_t)NROWS * NHEADS;                 // 64 x 1024   f32

    cast_all_kernel<<<(NX_C + NWI_C + NWO_C) / 256, 256, 0, stream>>>(
        x, in_proj_w, out_proj_w, buf_hb, buf_wi, buf_wo);

    for (int i = 0; i < 2; i++) {
        gemm_mfma<__hip_bfloat16, true><<<dim3(ZXP / 128, NROWS / 128), 256, 0, stream>>>(
            (const short*)buf_hb, (const short*)(buf_wi + (size_t)i * ZXP * D_MODEL),
            (__hip_bfloat16*)buf_zx, buf_dt, ZXP, D_MODEL, D_MODEL);

        ssd_intra_kernel<<<BATCH * NCHUNK * NHEADS, 256, 0, stream>>>(
            buf_zx, buf_dt,
            dt_bias + i * NHEADS, A_log + i * NHEADS,
            conv_w + (size_t)i * CONV_DIM * D_CONV, conv_b + (size_t)i * CONV_DIM,
            Dp + i * NHEADS, buf_ys, buf_S, buf_a, buf_cb);

        ssd_state_scan_kernel<<<BATCH * NHEADS * 4, 256, 0, stream>>>(buf_S, buf_a);

        if (i == 0) {
            ssd_finish_proj_kernel<__hip_bfloat16><<<BATCH * NCHUNK * 2, 512, 0, stream>>>(
                buf_cb, buf_zx, buf_ys, buf_S, buf_a,
                norm_w, (const u16*)buf_wo, (__hip_bfloat16*)buf_hb);
        } else {
            ssd_finish_proj_kernel<float><<<BATCH * NCHUNK * 2, 512, 0, stream>>>(
                buf_cb, buf_zx, buf_ys, buf_S, buf_a,
                norm_w + D_INNER, (const u16*)(buf_wo + (size_t)D_MODEL * D_INNER), out);
        }
    }
}